// Round 5
// baseline (413.620 us; speedup 1.0000x reference)
//
#include <hip/hip_runtime.h>
#include <hip/hip_bf16.h>

#define NU_ 200000
#define NS_ 100000
#define NT_ 100000
#define NN_ (NS_ + NU_ + NT_)   // 400000
#define D_ 32
#define DK_ 128
#define META_ 64
#define B_ 2048
#define L_ 50
#define NNZ_ 2000000
#define GK_ 8192                 // meta GEMM K = 64*128

#define RPB_ 391                 // rows per bucket
#define NB_ 1024                 // buckets (NB_*RPB_ = 400384 >= NN_)
#define STAGE_CAP_ 4096          // partition staging capacity (== edges/block: always taken)
#define CAPA_ 1280               // partA per-bucket capacity (mean ~830, sd ~29)
#define CAPB_ 512                // partB per-bucket capacity (mean ~180, sd ~13)
#define PEB_  4096               // partition edges per block
#define PE_GRID_ ((NNZ_ + PEB_ - 1) / PEB_)   // 489

// setup kernel block ranges: heavy attn first, then w2cvt, then streaming
#define SB_EMB_   6250           // NN_*4 / 256
#define IN4_SLOT3_ 100096        // 400384 ints / 4
#define IN4_MARKS_ 50048         // 800768 bytes / 16
#define IN4_E3C_   49152         // 196608 floats / 4
#define IN4_P0_    131072        // 2*2048*128 floats / 4
#define IN4_M1_   (IN4_SLOT3_ + IN4_MARKS_)                   // 150144
#define IN4_M2_   (IN4_M1_ + IN4_E3C_)                        // 199296
#define IN4_TOT_  (IN4_M2_ + IN4_P0_)                         // 330368
#define SB_INIT_  ((IN4_TOT_ + 2048 + 255) / 256)             // 1299
#define SB_ATT0_  0
#define SB_W2C0_  1024
#define SB_EMB0_  2048
#define SB_INIT0_ (SB_EMB0_ + SB_EMB_)                        // 8298
#define SB_GRID_  (SB_INIT0_ + SB_INIT_)                      // 9597

// prep kernel block ranges
#define PB_GATHER_ 192
#define PB_TOT_    (PB_GATHER_ + 1024)

// ncf tiling
#define NCF_TILE_ 16

typedef __attribute__((ext_vector_type(8))) short bf16x8;
typedef __attribute__((ext_vector_type(4))) float f32x4;

// single-instruction RNE pack of two f32 -> packed bf16x2 (lo=a, hi=b)
__device__ inline unsigned bfpack(float a, float b) {
    unsigned r;
    asm("v_cvt_pk_bf16_f32 %0, %1, %2" : "=v"(r) : "v"(a), "v"(b));
    return r;
}
__device__ inline float bf2f(short s) {
    return __uint_as_float(((unsigned)(unsigned short)s) << 16);
}

// ===========================================================================
// Setup (fused): attn pooling | w2 cvt | emb bf16 table | workspace init.
// Heavy attn blocks launch FIRST to overlap under the BW-bound streaming.
// LDS kept small (~6.2KB) so streaming blocks retain high occupancy.
// ===========================================================================
__global__ __launch_bounds__(256) void setup_kernel(
    const float* __restrict__ item_s, const float* __restrict__ user_e,
    const float* __restrict__ item_t, unsigned short* __restrict__ tab,
    int* __restrict__ slot3, int* __restrict__ marks /* mark1|mark2 contiguous */,
    float* __restrict__ E3c, float* __restrict__ P0,
    int* __restrict__ bcurA, int* __restrict__ bcurB,
    // attn pooling
    const int* __restrict__ u,
    const int* __restrict__ seq_s, const int* __restrict__ seq_t,
    const float* __restrict__ aw1_s, const float* __restrict__ ab1_s,
    const float* __restrict__ aw2_s,
    const float* __restrict__ aw1_t, const float* __restrict__ ab1_t,
    const float* __restrict__ aw2_t,
    float* __restrict__ his_s, float* __restrict__ his_t,
    // w2 cvt
    const float* __restrict__ dw2_s, const float* __restrict__ dw2_t,
    unsigned short* __restrict__ o_s, unsigned short* __restrict__ o_t)
{
    __shared__ float w1t[1024];     // transposed: w1t[i*32+jj] = w1[jj][i]
    __shared__ float b1s[32];
    __shared__ float w2s[32];
    __shared__ float att[4][64];
    __shared__ int   ids[4][52];

    int bid = blockIdx.x, t = threadIdx.x;
    if (bid < SB_W2C0_) {
        // ---- attention pooling: 4 samples per block (1 wave each), same dom ----
        int aid = bid;
        int dom = aid >> 9;
        const int* seq = dom ? seq_t : seq_s;
        const float* emb = dom ? item_t : item_s;
        const float* w1 = dom ? aw1_t : aw1_s;
        const float* b1 = dom ? ab1_t : ab1_s;
        const float* w2 = dom ? aw2_t : aw2_s;
        float* out = dom ? his_t : his_s;

        for (int idx = t; idx < 1024; idx += 256)
            w1t[(idx & 31) * 32 + (idx >> 5)] = w1[idx];
        if (t < 32) { b1s[t] = b1[t]; w2s[t] = w2[t]; }
        __syncthreads();

        int w = t >> 6, l = t & 63;
        int b = (aid & 511) * 4 + w;
        int uid = u[b];
        int lq = (l < L_) ? l : (L_ - 1);
        int id = seq[uid * L_ + lq];
        const float4* ep = (const float4*)(emb + (size_t)id * 32);
        float4 e4[8];
        #pragma unroll
        for (int q = 0; q < 8; q++) e4[q] = ep[q];
        float acc = 0.f;
        #pragma unroll
        for (int i = 0; i < 32; i++) {
            float hi = b1s[i];
            const float4* wr = (const float4*)(w1t + i * 32);
            #pragma unroll
            for (int jq = 0; jq < 8; jq++) {
                float4 wf = wr[jq];
                hi += e4[jq].x*wf.x + e4[jq].y*wf.y + e4[jq].z*wf.z + e4[jq].w*wf.w;
            }
            acc += fmaxf(hi, 0.f) * w2s[i];
        }
        float logit = (l < L_) ? (acc - (id == 0 ? 1e8f : 0.f)) : -1e30f;
        float m = logit;
        for (int off = 32; off > 0; off >>= 1) m = fmaxf(m, __shfl_down(m, off, 64));
        m = __shfl(m, 0, 64);
        float ex = (l < L_) ? expf(logit - m) : 0.f;
        float s = ex;
        for (int off = 32; off > 0; off >>= 1) s += __shfl_down(s, off, 64);
        s = __shfl(s, 0, 64);
        att[w][l] = ex / s;
        if (l < L_) ids[w][l] = id;
        __syncthreads();
        // weighted re-gather of e (L3-resident), split across half-waves
        {
            int d = l & 31, half = l >> 5;
            int q0 = half * 25;
            float o = 0.f;
            #pragma unroll
            for (int q = 0; q < 25; q++) {
                int qq = q0 + q;
                o += att[w][qq] * emb[(size_t)ids[w][qq] * 32 + d];
            }
            o += __shfl_xor(o, 32, 64);
            if (l < 32) out[b * 32 + l] = o;
        }
    } else if (bid < SB_EMB0_) {
        // ---- w2 -> bf16 transposed cvt (inputs only) ----
        int b3 = bid - SB_W2C0_;
        int dom = b3 >> 9, sub = b3 & 511;
        const float* w2 = dom ? dw2_t : dw2_s;
        unsigned short* o = dom ? o_t : o_s;
        int tid = sub * 256 + t;
        int nn = tid & 127, k8 = tid >> 7;
        float v[8];
        #pragma unroll
        for (int i = 0; i < 8; i++) v[i] = w2[(size_t)(k8 * 8 + i) * 128 + nn];
        uint4 r;
        r.x = bfpack(v[0], v[1]); r.y = bfpack(v[2], v[3]);
        r.z = bfpack(v[4], v[5]); r.w = bfpack(v[6], v[7]);
        *(uint4*)(o + (size_t)nn * GK_ + k8 * 8) = r;
    } else if (bid < SB_INIT0_) {
        int tid = (bid - SB_EMB0_) * 256 + t;            // < NN_*4
        int row = tid >> 2, seg = tid & 3;
        const float* src;
        if (row < NS_)            src = item_s + (size_t)row * 32;
        else if (row < NS_ + NU_) src = user_e + (size_t)(row - NS_) * 32;
        else                      src = item_t + (size_t)(row - NS_ - NU_) * 32;
        const float4* sp = (const float4*)(src + seg * 8);
        float4 a = sp[0], b = sp[1];
        uint4 r;
        r.x = bfpack(a.x, a.y); r.y = bfpack(a.z, a.w);
        r.z = bfpack(b.x, b.y); r.w = bfpack(b.z, b.w);
        *(uint4*)(tab + (size_t)row * 32 + seg * 8) = r;
    } else {
        int idx = (bid - SB_INIT0_) * 256 + t;
        if (idx < IN4_SLOT3_) {
            ((int4*)slot3)[idx] = make_int4(-1, -1, -1, -1);
        } else if (idx < IN4_M1_) {
            ((int4*)marks)[idx - IN4_SLOT3_] = make_int4(0, 0, 0, 0);
        } else if (idx < IN4_M2_) {
            ((int4*)E3c)[idx - IN4_M1_] = make_int4(0, 0, 0, 0);
        } else if (idx < IN4_TOT_) {
            ((int4*)P0)[idx - IN4_M2_] = make_int4(0, 0, 0, 0);
        } else {
            int c = idx - IN4_TOT_;
            if (c < NB_)            bcurA[c] = c * CAPA_;
            else if (c < 2 * NB_)   bcurB[c - NB_] = (c - NB_) * CAPB_;
        }
    }
}

// ===========================================================================
// Demand marking. Seeds: rows needed in E3 (and gathered from E1/E2).
// ===========================================================================
__global__ __launch_bounds__(256) void mark_seeds(
    const int* __restrict__ u, const int* __restrict__ si, const int* __restrict__ ti,
    int* __restrict__ slot3, unsigned char* __restrict__ mark1,
    unsigned char* __restrict__ mark2)
{
    int n = blockIdx.x * 256 + threadIdx.x;
    if (n >= 3 * B_) return;
    int which = n >> 11, b = n & (B_ - 1);
    int row = (which == 0) ? si[b] : (which == 1) ? NS_ + u[b] : NS_ + NU_ + ti[b];
    slot3[row] = n;          // racy for dup rows: any winner is fine (shared slot)
    mark1[row] = 1;
    mark2[row] = 1;
}

// mark propagation one hop backward: 4 edges/thread via int4 loads.
__global__ __launch_bounds__(256) void mark_pass(
    const int* __restrict__ rows, const int* __restrict__ cols,
    const int* __restrict__ slot3, const unsigned char* __restrict__ msrc,
    unsigned char* __restrict__ mdst, int use_slot)
{
    int j4 = blockIdx.x * 256 + threadIdx.x;
    if (j4 >= NNZ_ / 4) return;
    int4 r = ((const int4*)rows)[j4];
    int4 c = ((const int4*)cols)[j4];
    if (use_slot) {
        if (slot3[r.x] >= 0) mdst[c.x] = 1;
        if (slot3[r.y] >= 0) mdst[c.y] = 1;
        if (slot3[r.z] >= 0) mdst[c.z] = 1;
        if (slot3[r.w] >= 0) mdst[c.w] = 1;
    } else {
        if (msrc[r.x]) mdst[c.x] = 1;
        if (msrc[r.y]) mdst[c.y] = 1;
        if (msrc[r.z]) mdst[c.z] = 1;
        if (msrc[r.w]) mdst[c.w] = 1;
    }
}

// ===========================================================================
// One-pass partition into strided per-bucket regions (no global histogram).
// 490 blocks x 4096 edges (8/thread): ~2 blocks/CU, staged path always taken.
// Payload: meta = local_row<<19 | col ; val.
// ===========================================================================
__global__ __launch_bounds__(512) void partition_edges(
    const int* __restrict__ rows, const int* __restrict__ cols,
    const float* __restrict__ vals,
    const unsigned char* __restrict__ mark1, const unsigned char* __restrict__ mark2,
    int* __restrict__ bcurA, int* __restrict__ bcurB,
    int2* __restrict__ partA, int2* __restrict__ partB)
{
    __shared__ int hist[NB_], sstart[NB_], sbase[NB_], scur[NB_];
    __shared__ int2 stage[STAGE_CAP_];
    __shared__ unsigned short stageb[STAGE_CAP_];
    __shared__ int stotal;

    int t = threadIdx.x;
    for (int i = t; i < NB_; i += 512) hist[i] = 0;
    __syncthreads();

    int base = blockIdx.x * PEB_;
    int mybkt[8]; int2 mye[8]; unsigned myB = 0;
    #pragma unroll
    for (int i = 0; i < 8; i++) {
        int j = base + i * 512 + t;
        mybkt[i] = -1;
        if (j < NNZ_) {
            int r = rows[j];
            if (mark1[r]) {               // mark2 subset of mark1
                int bb = r / RPB_;
                int lr = r - bb * RPB_;
                mye[i] = make_int2((lr << 19) | cols[j], __float_as_int(vals[j]));
                mybkt[i] = bb;
                if (mark2[r]) myB |= (1u << i);
                atomicAdd(&hist[bb], 1);
            }
        }
    }
    __syncthreads();
    // ---- phase A: block-local scan of hist, reserve global runs, stage ----
    for (int i = t; i < NB_; i += 512) sstart[i] = hist[i];
    __syncthreads();
    for (int off = 1; off < NB_; off <<= 1) {
        int x0 = (t >= off) ? sstart[t - off] : 0;
        int x1 = (t + 512 >= off) ? sstart[t + 512 - off] : 0;
        __syncthreads();
        sstart[t] += x0; sstart[t + 512] += x1;
        __syncthreads();
    }
    if (t == 0) stotal = sstart[NB_ - 1];
    __syncthreads();
    int tot = stotal;
    for (int i = t; i < NB_; i += 512) {
        int cnt = hist[i];
        sstart[i] -= cnt;                             // exclusive
        sbase[i] = cnt ? atomicAdd(&bcurA[i], cnt) : 0;
        scur[i] = 0;
    }
    __syncthreads();

    // tot <= PEB_ == STAGE_CAP_: staged path always valid
    #pragma unroll
    for (int i = 0; i < 8; i++) {
        int bb = mybkt[i];
        if (bb >= 0) {
            int p = atomicAdd(&scur[bb], 1);
            int s = sstart[bb] + p;
            stage[s] = mye[i];
            stageb[s] = (unsigned short)bb;
        }
    }
    __syncthreads();
    for (int i = t; i < tot; i += 512) {
        int bb = stageb[i];
        int pos = sbase[bb] + (i - sstart[bb]);
        if (pos < (bb + 1) * CAPA_) partA[pos] = stage[i];
    }
    __syncthreads();
    // ---- phase B: aggregate counts, reserve, direct scatter ----
    for (int i = t; i < NB_; i += 512) hist[i] = 0;
    __syncthreads();
    #pragma unroll
    for (int i = 0; i < 8; i++)
        if (myB & (1u << i)) atomicAdd(&hist[mybkt[i]], 1);
    __syncthreads();
    for (int i = t; i < NB_; i += 512) {
        sbase[i] = hist[i] ? atomicAdd(&bcurB[i], hist[i]) : 0;
        scur[i] = 0;
    }
    __syncthreads();
    #pragma unroll
    for (int i = 0; i < 8; i++) {
        if (myB & (1u << i)) {
            int bb = mybkt[i];
            int p = atomicAdd(&scur[bb], 1);
            int pos = sbase[bb] + p;
            if (pos < (bb + 1) * CAPB_) partB[pos] = mye[i];
        }
    }
}

// ===========================================================================
// Bucket SpMV hop, NO fp atomics: edges register-staged (single global read),
// within-bucket counting sort by row (LDS histogram + scan + scatter), then
// per-row REGISTER accumulation.
// fgate (optional): write fp32 output only for rows with fgate[row]>=0.
// ===========================================================================
__global__ __launch_bounds__(512) void hop_csr(
    const int* __restrict__ bcur, const int2* __restrict__ part, int cap,
    const unsigned short* __restrict__ tab,
    const unsigned char* __restrict__ markw,
    const int* __restrict__ fgate,
    float* __restrict__ yf, unsigned short* __restrict__ ybf)
{
    __shared__ int2 sorted[CAPA_];        // 10.2 KB
    __shared__ int cnt[RPB_];             // counts -> cursors
    __shared__ int scanb[512];            // inclusive scan of counts

    int t = threadIdx.x;
    int bkt = blockIdx.x;
    int e0 = bkt * cap;
    int n = bcur[bkt] - e0;
    if (n > cap) n = cap;

    // register-stage up to 3 edges/thread (covers CAPA_=1280 and CAPB_=512)
    int2 mye[3]; int myl[3];
    #pragma unroll
    for (int i = 0; i < 3; i++) {
        int j = i * 512 + t;
        myl[i] = -1;
        if (j < n) {
            mye[i] = part[e0 + j];
            myl[i] = (mye[i].x >> 19) & 0x3FF;
        }
    }
    for (int i = t; i < RPB_; i += 512) cnt[i] = 0;
    __syncthreads();
    #pragma unroll
    for (int i = 0; i < 3; i++)
        if (myl[i] >= 0) atomicAdd(&cnt[myl[i]], 1);
    __syncthreads();
    scanb[t] = (t < RPB_) ? cnt[t] : 0;
    __syncthreads();
    for (int off = 1; off < 512; off <<= 1) {
        int x = (t >= off) ? scanb[t - off] : 0;
        __syncthreads();
        scanb[t] += x;
        __syncthreads();
    }
    if (t < RPB_) cnt[t] = scanb[t] - cnt[t];
    __syncthreads();
    #pragma unroll
    for (int i = 0; i < 3; i++)
        if (myl[i] >= 0) {
            int p2 = atomicAdd(&cnt[myl[i]], 1);
            sorted[p2] = mye[i];
        }
    __syncthreads();
    int chunk = t & 3;
    int row0 = bkt * RPB_;
    for (int r = t >> 2; r < RPB_; r += 128) {
        int grow = row0 + r;
        if (grow >= NN_ || !markw[grow]) continue;
        int eb = (r == 0) ? 0 : scanb[r - 1];
        int ee = scanb[r];
        float racc[8] = {0.f, 0.f, 0.f, 0.f, 0.f, 0.f, 0.f, 0.f};
        for (int e = eb; e < ee; e++) {
            int2 ed = sorted[e];
            int col = ed.x & 0x7FFFF;
            float vv = __int_as_float(ed.y);
            bf16x8 x = *(const bf16x8*)(tab + (size_t)col * 32 + chunk * 8);
            #pragma unroll
            for (int k = 0; k < 8; k++) racc[k] += vv * bf2f(x[k]);
        }
        float4 o0 = {racc[0], racc[1], racc[2], racc[3]};
        float4 o1 = {racc[4], racc[5], racc[6], racc[7]};
        if (!fgate || fgate[grow] >= 0) {
            float4* yp = (float4*)(yf + (size_t)grow * 32 + chunk * 8);
            yp[0] = o0; yp[1] = o1;
        }
        if (ybf) {
            uint4 pk;
            pk.x = bfpack(o0.x, o0.y); pk.y = bfpack(o0.z, o0.w);
            pk.z = bfpack(o1.x, o1.y); pk.w = bfpack(o1.z, o1.w);
            *(uint4*)(ybf + (size_t)grow * 32 + chunk * 8) = pk;
        }
    }
}

// ===========================================================================
// Hop 3 over compact partB: global atomics into E3c (fp32 E2 source).
// ===========================================================================
__global__ __launch_bounds__(256) void hop3_part(
    const int* __restrict__ bcurB, const int2* __restrict__ partB,
    const int* __restrict__ slot3,
    const float* __restrict__ E2, float* __restrict__ E3c)
{
    int t = threadIdx.x;
    int bkt = blockIdx.x;
    int e0 = bkt * CAPB_;
    int e1 = bcurB[bkt];
    int emax = e0 + CAPB_;
    if (e1 > emax) e1 = emax;
    int c = t & 7;
    for (int i = e0 + (t >> 3); i < e1; i += 32) {
        int2 e = partB[i];
        int lr = (e.x >> 19) & 0x3FF;
        int s = slot3[bkt * RPB_ + lr];
        if (s < 0) continue;
        int col = e.x & 0x7FFFF;
        float v = __int_as_float(e.y);
        float4 xv = ((const float4*)E2)[(size_t)col * 8 + c];
        float* p = E3c + (size_t)s * 32 + c * 4;
        unsafeAtomicAdd(p + 0, v * xv.x);
        unsafeAtomicAdd(p + 1, v * xv.y);
        unsafeAtomicAdd(p + 2, v * xv.z);
        unsafeAtomicAdd(p + 3, v * xv.w);
    }
}

// ===========================================================================
// Prep (fused): [0,192) gather_simple | [192,1216) h_relu
// ===========================================================================
__global__ __launch_bounds__(256) void prep_kernel(
    // gather
    const float* __restrict__ E1, const float* __restrict__ E2,
    const float* __restrict__ E3c, const int* __restrict__ slot3,
    const int* __restrict__ u, const int* __restrict__ si, const int* __restrict__ ti,
    const float* __restrict__ user_emb, const float* __restrict__ item_s,
    const float* __restrict__ item_t,
    float* __restrict__ u_e, float* __restrict__ si_e, float* __restrict__ ti_e,
    // h_relu
    const float* __restrict__ his_s, const float* __restrict__ his_t,
    const float* __restrict__ dw1_s, const float* __restrict__ db1_s,
    const float* __restrict__ dw1_t, const float* __restrict__ db1_t,
    float* __restrict__ h_s, float* __restrict__ h_t)
{
    int bid = blockIdx.x, t = threadIdx.x;
    if (bid < PB_GATHER_) {
        int tid = bid * 256 + t;
        if (tid >= 3 * B_ * 8) return;
        int n = tid >> 3, c = tid & 7;
        int which = n >> 11, b = n & (B_ - 1);
        int row;
        const float4* base0;
        float* outp;
        if (which == 0)      { int id = si[b]; row = id;             base0 = (const float4*)item_s + (size_t)id * 8; outp = si_e; }
        else if (which == 1) { int id = u[b];  row = NS_ + id;       base0 = (const float4*)user_emb + (size_t)id * 8; outp = u_e; }
        else                 { int id = ti[b]; row = NS_ + NU_ + id; base0 = (const float4*)item_t + (size_t)id * 8; outp = ti_e; }
        float4 k0 = base0[c];
        float4 k1 = ((const float4*)E1)[(size_t)row * 8 + c];
        float4 k2 = ((const float4*)E2)[(size_t)row * 8 + c];
        float4 k3 = ((const float4*)E3c)[(size_t)slot3[row] * 8 + c];
        float4* orow = (float4*)(outp + (size_t)b * 128);
        orow[0 * 8 + c] = k0;
        orow[1 * 8 + c] = k1;
        orow[2 * 8 + c] = k2;
        orow[3 * 8 + c] = k3;
    } else {
        int b2 = bid - PB_GATHER_;
        int dom = b2 >> 9, sub = b2 & 511;
        const float* his = dom ? his_t : his_s;
        const float* w1  = dom ? dw1_t : dw1_s;
        const float* b1  = dom ? db1_t : db1_s;
        float* h         = dom ? h_t   : h_s;
        int b = sub * 4 + (t >> 6);
        int m = t & 63;
        float acc = b1[m];
        #pragma unroll
        for (int j = 0; j < 32; j++) acc += his[b * 32 + j] * w1[j * 64 + m];
        h[b * 64 + m] = fmaxf(acc, 0.f);
    }
}

// ===========================================================================
// Meta GEMM (bf16 MFMA): out[b,e] = sum_k q[b,k] * w2t[e,k],
// q[b, m*128+d] = h[b,m]*u_e[b,d] generated during LDS staging.
// Block: 64x128 tile, 4 waves 2x2. Split-K = 8 -> atomic accumulate into P0.
// ===========================================================================
__global__ __launch_bounds__(256) void meta_gemm(
    const float* __restrict__ h_s, const float* __restrict__ h_t,
    const float* __restrict__ ue,
    const unsigned short* __restrict__ w2t_s, const unsigned short* __restrict__ w2t_t,
    float* __restrict__ P0)     // [2][B][128], zero-init in setup
{
    __shared__ unsigned short As[64 * 72];
    __shared__ unsigned short Bs[128 * 72];

    int mt = blockIdx.x & 31, dom = blockIdx.x >> 5;
    int ks = blockIdx.y;
    const float* h = dom ? h_t : h_s;
    const unsigned short* w2t = dom ? w2t_t : w2t_s;

    int t = threadIdx.x;
    int ar = t >> 2, aseg = t & 3;
    int bn = t >> 1, bhalf = t & 1;
    int w = t >> 6, lane = t & 63;
    int quad = lane >> 4, l16 = lane & 15;
    int wm = (w & 1) * 32, wn = (w >> 1) * 64;

    f32x4 acc[8];
    #pragma unroll
    for (int i = 0; i < 8; i++) { acc[i][0]=0.f; acc[i][1]=0.f; acc[i][2]=0.f; acc[i][3]=0.f; }

    for (int ch = 0; ch < 16; ch++) {
        int kb = ks * 1024 + ch * 64;
        __syncthreads();
        {
            int gm = mt * 64 + ar;
            int m_idx = kb >> 7;
            int d0 = (kb & 127) + aseg * 16;
            float hv = h[gm * 64 + m_idx];
            const float4* up = (const float4*)(ue + (size_t)gm * 128 + d0);
            float4 x0 = up[0], x1 = up[1], x2 = up[2], x3 = up[3];
            uint4 A0, A1;
            A0.x = bfpack(hv*x0.x, hv*x0.y); A0.y = bfpack(hv*x0.z, hv*x0.w);
            A0.z = bfpack(hv*x1.x, hv*x1.y); A0.w = bfpack(hv*x1.z, hv*x1.w);
            A1.x = bfpack(hv*x2.x, hv*x2.y); A1.y = bfpack(hv*x2.z, hv*x2.w);
            A1.z = bfpack(hv*x3.x, hv*x3.y); A1.w = bfpack(hv*x3.z, hv*x3.w);
            uint4* sa = (uint4*)(As + ar * 72 + aseg * 16);
            sa[0] = A0; sa[1] = A1;
        }
        {
            const uint4* gb = (const uint4*)(w2t + (size_t)bn * GK_ + kb + bhalf * 32);
            uint4* sb = (uint4*)(Bs + bn * 72 + bhalf * 32);
            sb[0] = gb[0]; sb[1] = gb[1]; sb[2] = gb[2]; sb[3] = gb[3];
        }
        __syncthreads();
        #pragma unroll
        for (int kk = 0; kk < 2; kk++) {
            int ko = kk * 32 + quad * 8;
            bf16x8 a0 = *(const bf16x8*)(As + (wm + l16) * 72 + ko);
            bf16x8 a1 = *(const bf16x8*)(As + (wm + 16 + l16) * 72 + ko);
            #pragma unroll
            for (int nt = 0; nt < 4; nt++) {
                bf16x8 bfr = *(const bf16x8*)(Bs + (wn + nt * 16 + l16) * 72 + ko);
                acc[nt]     = __builtin_amdgcn_mfma_f32_16x16x32_bf16(a0, bfr, acc[nt],     0, 0, 0);
                acc[4 + nt] = __builtin_amdgcn_mfma_f32_16x16x32_bf16(a1, bfr, acc[4 + nt], 0, 0, 0);
            }
        }
    }
    float* op = P0 + (size_t)dom * B_ * 128;
    #pragma unroll
    for (int ma = 0; ma < 2; ma++)
        #pragma unroll
        for (int nt = 0; nt < 4; nt++) {
            int row = mt * 64 + wm + ma * 16 + quad * 4;
            int col = wn + nt * 16 + l16;
            f32x4 v = acc[ma * 4 + nt];
            unsafeAtomicAdd(&op[(size_t)(row + 0) * 128 + col], v[0]);
            unsafeAtomicAdd(&op[(size_t)(row + 1) * 128 + col], v[1]);
            unsafeAtomicAdd(&op[(size_t)(row + 2) * 128 + col], v[2]);
            unsafeAtomicAdd(&op[(size_t)(row + 3) * 128 + col], v[3]);
        }
}

// ===========================================================================
// NCF heads, tiled: grid (B_/16, 2), 512 threads, 16 samples per block.
// Weights read once per 16 samples; 4-sample register blocking with float4
// LDS broadcast reads (4 independent FMA chains per thread).
// x = [ P0[dom][b] + u_e@b2meta | pair_e ]
// ===========================================================================
__global__ __launch_bounds__(512) void ncf_kernel(
    const float* __restrict__ P0, const float* __restrict__ u_e,
    const float* __restrict__ b2_s, const float* __restrict__ b2_t,
    const float* __restrict__ si_e, const float* __restrict__ ti_e,
    const float* __restrict__ w1_s, const float* __restrict__ b1_s,
    const float* __restrict__ w2_s, const float* __restrict__ bb2_s,
    const float* __restrict__ dw_s, const float* __restrict__ db_s,
    const float* __restrict__ w1_t, const float* __restrict__ b1_t,
    const float* __restrict__ w2_t, const float* __restrict__ bb2_t,
    const float* __restrict__ dw_t, const float* __restrict__ db_t,
    float* __restrict__ out)
{
    int tile = blockIdx.x, dom = blockIdx.y, t = threadIdx.x;
    int b0 = tile * NCF_TILE_;
    const float* Pd     = P0 + (size_t)dom * B_ * 128;
    const float* b2meta = dom ? b2_t : b2_s;
    const float* pair_e = dom ? ti_e : si_e;
    const float* w1 = dom ? w1_t : w1_s;
    const float* b1 = dom ? b1_t : b1_s;
    const float* w2 = dom ? w2_t : w2_s;
    const float* bb2 = dom ? bb2_t : bb2_s;
    const float* dw = dom ? dw_t : dw_s;
    const float* db = dom ? db_t : db_s;

    __shared__ float ues[NCF_TILE_ * 128];   // 8 KB
    __shared__ float xs[NCF_TILE_ * 256];    // 16 KB
    __shared__ float h1s[NCF_TILE_ * 128];   // 8 KB
    __shared__ float h2s[NCF_TILE_ * 64];    // 4 KB

    // stage u_e tile and pair_e (into x second half); 2048 floats each
    {
        float4 v = ((const float4*)(u_e + (size_t)b0 * 128))[t];
        ((float4*)ues)[t] = v;
        float4 pv = ((const float4*)(pair_e + (size_t)b0 * 128))[t];
        int s = t >> 5, c4 = t & 31;
        ((float4*)(xs + s * 256 + 128))[c4] = pv;
    }
    __syncthreads();

    int j = t & 127, g = t >> 7;          // 4 groups x 4 samples
    // ---- phase 1: x[:,0:128] = P0 + ue @ b2meta ----
    {
        float acc[4];
        #pragma unroll
        for (int ss = 0; ss < 4; ss++) {
            int b = b0 + g * 4 + ss;
            acc[ss] = Pd[(size_t)b * 128 + j];
        }
        for (int dc = 0; dc < 32; dc++) {
            float wa = b2meta[(dc * 4 + 0) * 128 + j];
            float wb = b2meta[(dc * 4 + 1) * 128 + j];
            float wc = b2meta[(dc * 4 + 2) * 128 + j];
            float wd = b2meta[(dc * 4 + 3) * 128 + j];
            #pragma unroll
            for (int ss = 0; ss < 4; ss++) {
                float4 uv = ((const float4*)(ues + (g * 4 + ss) * 128))[dc];
                acc[ss] += uv.x * wa + uv.y * wb + uv.z * wc + uv.w * wd;
            }
        }
        #pragma unroll
        for (int ss = 0; ss < 4; ss++) xs[(g * 4 + ss) * 256 + j] = acc[ss];
    }
    __syncthreads();

    // ---- phase 2: h1 = relu(x @ w1 + b1) ----
    {
        float b1v = b1[j];
        float acc[4] = {b1v, b1v, b1v, b1v};
        for (int kc = 0; kc < 64; kc++) {
            float wa = w1[(kc * 4 + 0) * 128 + j];
            float wb = w1[(kc * 4 + 1) * 128 + j];
            float wc = w1[(kc * 4 + 2) * 128 + j];
            float wd = w1[(kc * 4 + 3) * 128 + j];
            #pragma unroll
            for (int ss = 0; ss < 4; ss++) {
                float4 xv = ((const float4*)(xs + (g * 4 + ss) * 256))[kc];
                acc[ss] += xv.x * wa + xv.y * wb + xv.z * wc + xv.w * wd;
            }
        }
        #pragma unroll
        for (int ss = 0; ss < 4; ss++)
            h1s[(g * 4 + ss) * 128 + j] = fmaxf(acc[ss], 0.f);
    }
    __syncthreads();

    // ---- phase 3: h2 = relu(h1 @ w2 + bb2) ----
    {
        int m = t & 63, g2 = t >> 6;      // 8 groups x 2 samples
        float bv = bb2[m];
        float acc[2] = {bv, bv};
        for (int kc = 0; kc < 32; kc++) {
            float wa = w2[(kc * 4 + 0) * 64 + m];
            float wb = w2[(kc * 4 + 1) * 64 + m];
            float wc = w2[(kc * 4 + 2) * 64 + m];
            float wd = w2[(kc * 4 + 3) * 64 + m];
            #pragma unroll
            for (int ss = 0; ss < 2; ss++) {
                float4 hv = ((const float4*)(h1s + (g2 * 2 + ss) * 128))[kc];
                acc[ss] += hv.x * wa + hv.y * wb + hv.z * wc + hv.w * wd;
            }
        }
        #pragma unroll
        for (int ss = 0; ss < 2; ss++)
            h2s[(g2 * 2 + ss) * 64 + m] = fmaxf(acc[ss], 0.f);
    }
    __syncthreads();

    // ---- phase 4: out = sigmoid(h2 @ dw + db) ----
    {
        int s = t >> 5, l = t & 31;
        float sum = h2s[s * 64 + l] * dw[l] + h2s[s * 64 + 32 + l] * dw[32 + l];
        #pragma unroll
        for (int off = 16; off > 0; off >>= 1) sum += __shfl_down(sum, off, 32);
        if (l == 0) {
            float z = sum + db[0];
            out[(size_t)dom * B_ + b0 + s] = 1.f / (1.f + expf(-z));
        }
    }
}

// ===========================================================================
extern "C" void kernel_launch(void* const* d_in, const int* in_sizes, int n_in,
                              void* d_out, int out_size, void* d_ws, size_t ws_size,
                              hipStream_t stream)
{
    const int*   u          = (const int*)  d_in[0];
    const int*   si         = (const int*)  d_in[1];
    const int*   ti         = (const int*)  d_in[2];
    const int*   src_seq    = (const int*)  d_in[3];
    const int*   tgt_seq    = (const int*)  d_in[4];
    const int*   adj_rows   = (const int*)  d_in[5];
    const int*   adj_cols   = (const int*)  d_in[6];
    const float* adj_vals   = (const float*)d_in[7];
    const float* user_emb   = (const float*)d_in[8];
    const float* item_s_emb = (const float*)d_in[9];
    const float* item_t_emb = (const float*)d_in[10];
    const float* attn_s_w1  = (const float*)d_in[11];
    const float* attn_s_b1  = (const float*)d_in[12];
    const float* attn_s_w2  = (const float*)d_in[13];
    const float* attn_t_w1  = (const float*)d_in[14];
    const float* attn_t_b1  = (const float*)d_in[15];
    const float* attn_t_w2  = (const float*)d_in[16];
    const float* dec_ss_w1  = (const float*)d_in[17];
    const float* dec_ss_b1  = (const float*)d_in[18];
    const float* dec_ss_w2  = (const float*)d_in[19];
    const float* dec_ss_b2  = (const float*)d_in[20];
    const float* dec_tt_w1  = (const float*)d_in[21];
    const float* dec_tt_b1  = (const float*)d_in[22];
    const float* dec_tt_w2  = (const float*)d_in[23];
    const float* dec_tt_b2  = (const float*)d_in[24];
    const float* mlp_s_w1   = (const float*)d_in[25];
    const float* mlp_s_b1   = (const float*)d_in[26];
    const float* mlp_s_w2   = (const float*)d_in[27];
    const float* mlp_s_b2   = (const float*)d_in[28];
    const float* dense_s_w  = (const float*)d_in[29];
    const float* dense_s_b  = (const float*)d_in[30];
    const float* mlp_t_w1   = (const float*)d_in[31];
    const float* mlp_t_b1   = (const float*)d_in[32];
    const float* mlp_t_w2   = (const float*)d_in[33];
    const float* mlp_t_b2   = (const float*)d_in[34];
    const float* dense_t_w  = (const float*)d_in[35];
    const float* dense_t_b  = (const float*)d_in[36];

    // workspace layout (all offsets 16B-aligned)
    char* p = (char*)d_ws;
    float* E1    = (float*)p;              p += (size_t)NN_ * 32 * 4;        // 51.2 MB
    float* E2    = (float*)p;              p += (size_t)NN_ * 32 * 4;        // 51.2 MB
    unsigned short* Ebf  = (unsigned short*)p; p += (size_t)NN_ * 32 * 2;    // 25.6 MB
    unsigned short* E1bf = (unsigned short*)p; p += (size_t)NN_ * 32 * 2;    // 25.6 MB
    int2*  partA = (int2*)p;               p += (size_t)NB_ * CAPA_ * 8;     // 10.5 MB
    int2*  partB = (int2*)p;               p += (size_t)NB_ * CAPB_ * 8;     // 4.2 MB
    int*   slot3 = (int*)p;                p += (size_t)400384 * 4;
    int*   marks = (int*)p;                                                  // mark1|mark2
    unsigned char* mark1 = (unsigned char*)p; p += 400384;
    unsigned char* mark2 = (unsigned char*)p; p += 400384;
    float* E3c   = (float*)p;              p += (size_t)3 * B_ * 32 * 4;     // 786 KB
    int*   bcurA = (int*)p;                p += NB_ * 4;
    int*   bcurB = (int*)p;                p += NB_ * 4;
    float* his_s = (float*)p;              p += (size_t)B_ * 32 * 4;
    float* his_t = (float*)p;              p += (size_t)B_ * 32 * 4;
    float* u_e   = (float*)p;              p += (size_t)B_ * 128 * 4;
    float* si_e  = (float*)p;              p += (size_t)B_ * 128 * 4;
    float* ti_e  = (float*)p;              p += (size_t)B_ * 128 * 4;
    float* h_s   = (float*)p;              p += (size_t)B_ * 64 * 4;
    float* h_t   = (float*)p;              p += (size_t)B_ * 64 * 4;
    float* P0    = (float*)p;              p += (size_t)2 * B_ * 128 * 4;    // 2 MB
    unsigned short* w2t_s = (unsigned short*)p; p += (size_t)128 * GK_ * 2;
    unsigned short* w2t_t = (unsigned short*)p; p += (size_t)128 * GK_ * 2;

    // 1. setup (fused): attn + w2 cvt + emb bf16 table + init (heavy blocks first)
    setup_kernel<<<SB_GRID_, 256, 0, stream>>>(item_s_emb, user_emb, item_t_emb,
                                               Ebf, slot3, marks, E3c, P0, bcurA, bcurB,
                                               u, src_seq, tgt_seq,
                                               attn_s_w1, attn_s_b1, attn_s_w2,
                                               attn_t_w1, attn_t_b1, attn_t_w2,
                                               his_s, his_t,
                                               dec_ss_w2, dec_tt_w2, w2t_s, w2t_t);
    // 2. seeds
    mark_seeds<<<24, 256, 0, stream>>>(u, si, ti, slot3, mark1, mark2);
    // 3-4. demand marking (4 edges/thread)
    int m4Blocks = (NNZ_ / 4 + 255) / 256;
    mark_pass<<<m4Blocks, 256, 0, stream>>>(adj_rows, adj_cols, slot3, mark2, mark2, 1);
    mark_pass<<<m4Blocks, 256, 0, stream>>>(adj_rows, adj_cols, slot3, mark2, mark1, 0);
    // 5. one-pass bucket partition (490 blocks x 4096 edges)
    partition_edges<<<PE_GRID_, 512, 0, stream>>>(adj_rows, adj_cols, adj_vals,
                                                  mark1, mark2, bcurA, bcurB, partA, partB);
    // 6-8. graph propagation (E1 fp32 gated to slot3 rows only)
    hop_csr<<<NB_, 512, 0, stream>>>(bcurA, partA, CAPA_, Ebf,  mark1, slot3, E1, E1bf);
    hop_csr<<<NB_, 512, 0, stream>>>(bcurB, partB, CAPB_, E1bf, mark2, nullptr, E2, nullptr);
    hop3_part<<<NB_, 256, 0, stream>>>(bcurB, partB, slot3, E2, E3c);
    // 9. prep: gather + h_relu
    prep_kernel<<<PB_TOT_, 256, 0, stream>>>(E1, E2, E3c, slot3, u, si, ti,
                                             user_emb, item_s_emb, item_t_emb,
                                             u_e, si_e, ti_e,
                                             his_s, his_t,
                                             dec_ss_w1, dec_ss_b1,
                                             dec_tt_w1, dec_tt_b1, h_s, h_t);
    // 10. meta MFMA GEMM (atomic split-K accumulate into P0)
    meta_gemm<<<dim3(64, 8), 256, 0, stream>>>(h_s, h_t, u_e, w2t_s, w2t_t, P0);
    // 11. NCF heads (both domains, 16-sample tiles)
    ncf_kernel<<<dim3(B_ / NCF_TILE_, 2), 512, 0, stream>>>(P0, u_e, dec_ss_b2, dec_tt_b2,
                                                si_e, ti_e,
                                                mlp_s_w1, mlp_s_b1, mlp_s_w2, mlp_s_b2,
                                                dense_s_w, dense_s_b,
                                                mlp_t_w1, mlp_t_b1, mlp_t_w2, mlp_t_b2,
                                                dense_t_w, dense_t_b,
                                                (float*)d_out);
}

// Round 6
// 407.022 us; speedup vs baseline: 1.0162x; 1.0162x over previous
//
#include <hip/hip_runtime.h>
#include <hip/hip_bf16.h>

#define NU_ 200000
#define NS_ 100000
#define NT_ 100000
#define NN_ (NS_ + NU_ + NT_)   // 400000
#define D_ 32
#define DK_ 128
#define META_ 64
#define B_ 2048
#define L_ 50
#define NNZ_ 2000000
#define GK_ 8192                 // meta GEMM K = 64*128

#define RPB_ 391                 // rows per bucket
#define NB_ 1024                 // buckets (NB_*RPB_ = 400384 >= NN_)
#define STAGE_CAP_ 4096          // partition staging capacity (>10 sigma margin)
#define CAPA_ 1280               // partA per-bucket capacity (mean ~830, sd ~29)
#define CAPB_ 512                // partB per-bucket capacity (mean ~180, sd ~13)

// setup kernel block ranges: heavy attn first, then w2cvt, then streaming
#define SB_EMB_   6250           // NN_*4 / 256
#define IN4_SLOT3_ 100096        // 400384 ints / 4
#define IN4_MARKS_ 50048         // 800768 bytes / 16
#define IN4_E3C_   49152        // 196608 floats / 4
#define IN4_TOT_  (IN4_SLOT3_ + IN4_MARKS_ + IN4_E3C_)        // 199296
#define SB_INIT_  ((IN4_TOT_ + 2048 + 255) / 256)             // 787
#define SB_ATT0_  0
#define SB_W2C0_  1024
#define SB_EMB0_  2048
#define SB_INIT0_ (SB_EMB0_ + SB_EMB_)                        // 8298
#define SB_GRID_  (SB_INIT0_ + SB_INIT_)                      // 9085

// prep kernel block ranges
#define PB_GATHER_ 192
#define PB_TOT_    (PB_GATHER_ + 1024)

// ncf tiling
#define NCF_TILE_ 16

typedef __attribute__((ext_vector_type(8))) short bf16x8;
typedef __attribute__((ext_vector_type(4))) float f32x4;

// single-instruction RNE pack of two f32 -> packed bf16x2 (lo=a, hi=b)
__device__ inline unsigned bfpack(float a, float b) {
    unsigned r;
    asm("v_cvt_pk_bf16_f32 %0, %1, %2" : "=v"(r) : "v"(a), "v"(b));
    return r;
}
__device__ inline float bf2f(short s) {
    return __uint_as_float(((unsigned)(unsigned short)s) << 16);
}

// ===========================================================================
// Setup (fused): attn pooling | w2 cvt | emb bf16 table | workspace init.
// Heavy attn blocks launch FIRST to overlap under the BW-bound streaming.
// LDS kept small (~6.2KB) so streaming blocks retain high occupancy.
// ===========================================================================
__global__ __launch_bounds__(256) void setup_kernel(
    const float* __restrict__ item_s, const float* __restrict__ user_e,
    const float* __restrict__ item_t, unsigned short* __restrict__ tab,
    int* __restrict__ slot3, int* __restrict__ marks /* mark1|mark2 contiguous */,
    float* __restrict__ E3c, int* __restrict__ bcurA, int* __restrict__ bcurB,
    // attn pooling
    const int* __restrict__ u,
    const int* __restrict__ seq_s, const int* __restrict__ seq_t,
    const float* __restrict__ aw1_s, const float* __restrict__ ab1_s,
    const float* __restrict__ aw2_s,
    const float* __restrict__ aw1_t, const float* __restrict__ ab1_t,
    const float* __restrict__ aw2_t,
    float* __restrict__ his_s, float* __restrict__ his_t,
    // w2 cvt
    const float* __restrict__ dw2_s, const float* __restrict__ dw2_t,
    unsigned short* __restrict__ o_s, unsigned short* __restrict__ o_t)
{
    __shared__ float w1t[1024];     // transposed: w1t[i*32+jj] = w1[jj][i]
    __shared__ float b1s[32];
    __shared__ float w2s[32];
    __shared__ float att[4][64];
    __shared__ int   ids[4][52];

    int bid = blockIdx.x, t = threadIdx.x;
    if (bid < SB_W2C0_) {
        // ---- attention pooling: 4 samples per block (1 wave each), same dom ----
        int aid = bid;
        int dom = aid >> 9;
        const int* seq = dom ? seq_t : seq_s;
        const float* emb = dom ? item_t : item_s;
        const float* w1 = dom ? aw1_t : aw1_s;
        const float* b1 = dom ? ab1_t : ab1_s;
        const float* w2 = dom ? aw2_t : aw2_s;
        float* out = dom ? his_t : his_s;

        for (int idx = t; idx < 1024; idx += 256)
            w1t[(idx & 31) * 32 + (idx >> 5)] = w1[idx];
        if (t < 32) { b1s[t] = b1[t]; w2s[t] = w2[t]; }
        __syncthreads();

        int w = t >> 6, l = t & 63;
        int b = (aid & 511) * 4 + w;
        int uid = u[b];
        int lq = (l < L_) ? l : (L_ - 1);
        int id = seq[uid * L_ + lq];
        const float4* ep = (const float4*)(emb + (size_t)id * 32);
        float4 e4[8];
        #pragma unroll
        for (int q = 0; q < 8; q++) e4[q] = ep[q];
        float acc = 0.f;
        #pragma unroll
        for (int i = 0; i < 32; i++) {
            float hi = b1s[i];
            const float4* wr = (const float4*)(w1t + i * 32);
            #pragma unroll
            for (int jq = 0; jq < 8; jq++) {
                float4 wf = wr[jq];
                hi += e4[jq].x*wf.x + e4[jq].y*wf.y + e4[jq].z*wf.z + e4[jq].w*wf.w;
            }
            acc += fmaxf(hi, 0.f) * w2s[i];
        }
        float logit = (l < L_) ? (acc - (id == 0 ? 1e8f : 0.f)) : -1e30f;
        float m = logit;
        for (int off = 32; off > 0; off >>= 1) m = fmaxf(m, __shfl_down(m, off, 64));
        m = __shfl(m, 0, 64);
        float ex = (l < L_) ? expf(logit - m) : 0.f;
        float s = ex;
        for (int off = 32; off > 0; off >>= 1) s += __shfl_down(s, off, 64);
        s = __shfl(s, 0, 64);
        att[w][l] = ex / s;
        if (l < L_) ids[w][l] = id;
        __syncthreads();
        // weighted re-gather of e (L3-resident), split across half-waves
        {
            int d = l & 31, half = l >> 5;
            int q0 = half * 25;
            float o = 0.f;
            #pragma unroll
            for (int q = 0; q < 25; q++) {
                int qq = q0 + q;
                o += att[w][qq] * emb[(size_t)ids[w][qq] * 32 + d];
            }
            o += __shfl_xor(o, 32, 64);
            if (l < 32) out[b * 32 + l] = o;
        }
    } else if (bid < SB_EMB0_) {
        // ---- w2 -> bf16 transposed cvt (inputs only) ----
        int b3 = bid - SB_W2C0_;
        int dom = b3 >> 9, sub = b3 & 511;
        const float* w2 = dom ? dw2_t : dw2_s;
        unsigned short* o = dom ? o_t : o_s;
        int tid = sub * 256 + t;
        int nn = tid & 127, k8 = tid >> 7;
        float v[8];
        #pragma unroll
        for (int i = 0; i < 8; i++) v[i] = w2[(size_t)(k8 * 8 + i) * 128 + nn];
        uint4 r;
        r.x = bfpack(v[0], v[1]); r.y = bfpack(v[2], v[3]);
        r.z = bfpack(v[4], v[5]); r.w = bfpack(v[6], v[7]);
        *(uint4*)(o + (size_t)nn * GK_ + k8 * 8) = r;
    } else if (bid < SB_INIT0_) {
        int tid = (bid - SB_EMB0_) * 256 + t;            // < NN_*4
        int row = tid >> 2, seg = tid & 3;
        const float* src;
        if (row < NS_)            src = item_s + (size_t)row * 32;
        else if (row < NS_ + NU_) src = user_e + (size_t)(row - NS_) * 32;
        else                      src = item_t + (size_t)(row - NS_ - NU_) * 32;
        const float4* sp = (const float4*)(src + seg * 8);
        float4 a = sp[0], b = sp[1];
        uint4 r;
        r.x = bfpack(a.x, a.y); r.y = bfpack(a.z, a.w);
        r.z = bfpack(b.x, b.y); r.w = bfpack(b.z, b.w);
        *(uint4*)(tab + (size_t)row * 32 + seg * 8) = r;
    } else {
        int idx = (bid - SB_INIT0_) * 256 + t;
        if (idx < IN4_SLOT3_) {
            ((int4*)slot3)[idx] = make_int4(-1, -1, -1, -1);
        } else if (idx < IN4_SLOT3_ + IN4_MARKS_) {
            ((int4*)marks)[idx - IN4_SLOT3_] = make_int4(0, 0, 0, 0);
        } else if (idx < IN4_TOT_) {
            ((int4*)E3c)[idx - IN4_SLOT3_ - IN4_MARKS_] = make_int4(0, 0, 0, 0);
        } else {
            int c = idx - IN4_TOT_;
            if (c < NB_)            bcurA[c] = c * CAPA_;
            else if (c < 2 * NB_)   bcurB[c - NB_] = (c - NB_) * CAPB_;
        }
    }
}

// ===========================================================================
// Demand marking. Seeds: rows needed in E3 (and gathered from E1/E2).
// ===========================================================================
__global__ __launch_bounds__(256) void mark_seeds(
    const int* __restrict__ u, const int* __restrict__ si, const int* __restrict__ ti,
    int* __restrict__ slot3, unsigned char* __restrict__ mark1,
    unsigned char* __restrict__ mark2)
{
    int n = blockIdx.x * 256 + threadIdx.x;
    if (n >= 3 * B_) return;
    int which = n >> 11, b = n & (B_ - 1);
    int row = (which == 0) ? si[b] : (which == 1) ? NS_ + u[b] : NS_ + NU_ + ti[b];
    slot3[row] = n;          // racy for dup rows: any winner is fine (shared slot)
    mark1[row] = 1;
    mark2[row] = 1;
}

// mark propagation one hop backward: 4 edges/thread via int4 loads.
__global__ __launch_bounds__(256) void mark_pass(
    const int* __restrict__ rows, const int* __restrict__ cols,
    const int* __restrict__ slot3, const unsigned char* __restrict__ msrc,
    unsigned char* __restrict__ mdst, int use_slot)
{
    int j4 = blockIdx.x * 256 + threadIdx.x;
    if (j4 >= NNZ_ / 4) return;
    int4 r = ((const int4*)rows)[j4];
    int4 c = ((const int4*)cols)[j4];
    if (use_slot) {
        if (slot3[r.x] >= 0) mdst[c.x] = 1;
        if (slot3[r.y] >= 0) mdst[c.y] = 1;
        if (slot3[r.z] >= 0) mdst[c.z] = 1;
        if (slot3[r.w] >= 0) mdst[c.w] = 1;
    } else {
        if (msrc[r.x]) mdst[c.x] = 1;
        if (msrc[r.y]) mdst[c.y] = 1;
        if (msrc[r.z]) mdst[c.z] = 1;
        if (msrc[r.w]) mdst[c.w] = 1;
    }
}

// ===========================================================================
// One-pass partition into strided per-bucket regions (no global histogram).
// 245 blocks x 8192 edges (16/thread): amortizes the fixed per-block
// 1024-bucket hist+scan cost (490-block variant regressed — round 5).
// Payload: meta = local_row<<19 | col ; val.
// ===========================================================================
__global__ __launch_bounds__(512) void partition_edges(
    const int* __restrict__ rows, const int* __restrict__ cols,
    const float* __restrict__ vals,
    const unsigned char* __restrict__ mark1, const unsigned char* __restrict__ mark2,
    int* __restrict__ bcurA, int* __restrict__ bcurB,
    int2* __restrict__ partA, int2* __restrict__ partB)
{
    __shared__ int hist[NB_], sstart[NB_], sbase[NB_], scur[NB_];
    __shared__ int2 stage[STAGE_CAP_];
    __shared__ unsigned short stageb[STAGE_CAP_];
    __shared__ int stotal;

    int t = threadIdx.x;
    for (int i = t; i < NB_; i += 512) hist[i] = 0;
    __syncthreads();

    int base = blockIdx.x * 8192;
    int mybkt[16]; int2 mye[16]; unsigned myB = 0;
    #pragma unroll
    for (int i = 0; i < 16; i++) {
        int j = base + i * 512 + t;
        mybkt[i] = -1;
        if (j < NNZ_) {
            int r = rows[j];
            if (mark1[r]) {               // mark2 subset of mark1
                int bb = r / RPB_;
                int lr = r - bb * RPB_;
                mye[i] = make_int2((lr << 19) | cols[j], __float_as_int(vals[j]));
                mybkt[i] = bb;
                if (mark2[r]) myB |= (1u << i);
                atomicAdd(&hist[bb], 1);
            }
        }
    }
    __syncthreads();
    // ---- phase A: block-local scan of hist, reserve global runs, stage ----
    for (int i = t; i < NB_; i += 512) sstart[i] = hist[i];
    __syncthreads();
    for (int off = 1; off < NB_; off <<= 1) {
        int x0 = (t >= off) ? sstart[t - off] : 0;
        int x1 = (t + 512 >= off) ? sstart[t + 512 - off] : 0;
        __syncthreads();
        sstart[t] += x0; sstart[t + 512] += x1;
        __syncthreads();
    }
    if (t == 0) stotal = sstart[NB_ - 1];
    __syncthreads();
    int tot = stotal;
    for (int i = t; i < NB_; i += 512) {
        int cnt = hist[i];
        sstart[i] -= cnt;                             // exclusive
        sbase[i] = cnt ? atomicAdd(&bcurA[i], cnt) : 0;
        scur[i] = 0;
    }
    __syncthreads();

    if (tot <= STAGE_CAP_) {
        #pragma unroll
        for (int i = 0; i < 16; i++) {
            int bb = mybkt[i];
            if (bb >= 0) {
                int p = atomicAdd(&scur[bb], 1);
                int s = sstart[bb] + p;
                stage[s] = mye[i];
                stageb[s] = (unsigned short)bb;
            }
        }
        __syncthreads();
        for (int i = t; i < tot; i += 512) {
            int bb = stageb[i];
            int pos = sbase[bb] + (i - sstart[bb]);
            if (pos < (bb + 1) * CAPA_) partA[pos] = stage[i];
        }
    } else {
        // overflow fallback (statistically unreachable): direct scatter
        #pragma unroll
        for (int i = 0; i < 16; i++) {
            int bb = mybkt[i];
            if (bb >= 0) {
                int p = atomicAdd(&scur[bb], 1);
                int pos = sbase[bb] + p;
                if (pos < (bb + 1) * CAPA_) partA[pos] = mye[i];
            }
        }
    }
    __syncthreads();
    // ---- phase B: aggregate counts, reserve, direct scatter ----
    for (int i = t; i < NB_; i += 512) hist[i] = 0;
    __syncthreads();
    #pragma unroll
    for (int i = 0; i < 16; i++)
        if (myB & (1u << i)) atomicAdd(&hist[mybkt[i]], 1);
    __syncthreads();
    for (int i = t; i < NB_; i += 512) {
        sbase[i] = hist[i] ? atomicAdd(&bcurB[i], hist[i]) : 0;
        scur[i] = 0;
    }
    __syncthreads();
    #pragma unroll
    for (int i = 0; i < 16; i++) {
        if (myB & (1u << i)) {
            int bb = mybkt[i];
            int p = atomicAdd(&scur[bb], 1);
            int pos = sbase[bb] + p;
            if (pos < (bb + 1) * CAPB_) partB[pos] = mye[i];
        }
    }
}

// ===========================================================================
// Bucket SpMV hop, NO fp atomics: edges register-staged (single global read),
// within-bucket counting sort by row (LDS histogram + scan + scatter), then
// per-row REGISTER accumulation.
// fgate (optional): write fp32 output only for rows with fgate[row]>=0.
// ===========================================================================
__global__ __launch_bounds__(512) void hop_csr(
    const int* __restrict__ bcur, const int2* __restrict__ part, int cap,
    const unsigned short* __restrict__ tab,
    const unsigned char* __restrict__ markw,
    const int* __restrict__ fgate,
    float* __restrict__ yf, unsigned short* __restrict__ ybf)
{
    __shared__ int2 sorted[CAPA_];        // 10.2 KB
    __shared__ int cnt[RPB_];             // counts -> cursors
    __shared__ int scanb[512];            // inclusive scan of counts

    int t = threadIdx.x;
    int bkt = blockIdx.x;
    int e0 = bkt * cap;
    int n = bcur[bkt] - e0;
    if (n > cap) n = cap;

    // register-stage up to 3 edges/thread (covers CAPA_=1280 and CAPB_=512)
    int2 mye[3]; int myl[3];
    #pragma unroll
    for (int i = 0; i < 3; i++) {
        int j = i * 512 + t;
        myl[i] = -1;
        if (j < n) {
            mye[i] = part[e0 + j];
            myl[i] = (mye[i].x >> 19) & 0x3FF;
        }
    }
    for (int i = t; i < RPB_; i += 512) cnt[i] = 0;
    __syncthreads();
    #pragma unroll
    for (int i = 0; i < 3; i++)
        if (myl[i] >= 0) atomicAdd(&cnt[myl[i]], 1);
    __syncthreads();
    scanb[t] = (t < RPB_) ? cnt[t] : 0;
    __syncthreads();
    for (int off = 1; off < 512; off <<= 1) {
        int x = (t >= off) ? scanb[t - off] : 0;
        __syncthreads();
        scanb[t] += x;
        __syncthreads();
    }
    if (t < RPB_) cnt[t] = scanb[t] - cnt[t];
    __syncthreads();
    #pragma unroll
    for (int i = 0; i < 3; i++)
        if (myl[i] >= 0) {
            int p2 = atomicAdd(&cnt[myl[i]], 1);
            sorted[p2] = mye[i];
        }
    __syncthreads();
    int chunk = t & 3;
    int row0 = bkt * RPB_;
    for (int r = t >> 2; r < RPB_; r += 128) {
        int grow = row0 + r;
        if (grow >= NN_ || !markw[grow]) continue;
        int eb = (r == 0) ? 0 : scanb[r - 1];
        int ee = scanb[r];
        float racc[8] = {0.f, 0.f, 0.f, 0.f, 0.f, 0.f, 0.f, 0.f};
        for (int e = eb; e < ee; e++) {
            int2 ed = sorted[e];
            int col = ed.x & 0x7FFFF;
            float vv = __int_as_float(ed.y);
            bf16x8 x = *(const bf16x8*)(tab + (size_t)col * 32 + chunk * 8);
            #pragma unroll
            for (int k = 0; k < 8; k++) racc[k] += vv * bf2f(x[k]);
        }
        float4 o0 = {racc[0], racc[1], racc[2], racc[3]};
        float4 o1 = {racc[4], racc[5], racc[6], racc[7]};
        if (!fgate || fgate[grow] >= 0) {
            float4* yp = (float4*)(yf + (size_t)grow * 32 + chunk * 8);
            yp[0] = o0; yp[1] = o1;
        }
        if (ybf) {
            uint4 pk;
            pk.x = bfpack(o0.x, o0.y); pk.y = bfpack(o0.z, o0.w);
            pk.z = bfpack(o1.x, o1.y); pk.w = bfpack(o1.z, o1.w);
            *(uint4*)(ybf + (size_t)grow * 32 + chunk * 8) = pk;
        }
    }
}

// ===========================================================================
// Hop 3 over compact partB: global atomics into E3c (fp32 E2 source).
// ===========================================================================
__global__ __launch_bounds__(256) void hop3_part(
    const int* __restrict__ bcurB, const int2* __restrict__ partB,
    const int* __restrict__ slot3,
    const float* __restrict__ E2, float* __restrict__ E3c)
{
    int t = threadIdx.x;
    int bkt = blockIdx.x;
    int e0 = bkt * CAPB_;
    int e1 = bcurB[bkt];
    int emax = e0 + CAPB_;
    if (e1 > emax) e1 = emax;
    int c = t & 7;
    for (int i = e0 + (t >> 3); i < e1; i += 32) {
        int2 e = partB[i];
        int lr = (e.x >> 19) & 0x3FF;
        int s = slot3[bkt * RPB_ + lr];
        if (s < 0) continue;
        int col = e.x & 0x7FFFF;
        float v = __int_as_float(e.y);
        float4 xv = ((const float4*)E2)[(size_t)col * 8 + c];
        float* p = E3c + (size_t)s * 32 + c * 4;
        unsafeAtomicAdd(p + 0, v * xv.x);
        unsafeAtomicAdd(p + 1, v * xv.y);
        unsafeAtomicAdd(p + 2, v * xv.z);
        unsafeAtomicAdd(p + 3, v * xv.w);
    }
}

// ===========================================================================
// Prep (fused): [0,192) gather_simple | [192,1216) h_relu
// ===========================================================================
__global__ __launch_bounds__(256) void prep_kernel(
    // gather
    const float* __restrict__ E1, const float* __restrict__ E2,
    const float* __restrict__ E3c, const int* __restrict__ slot3,
    const int* __restrict__ u, const int* __restrict__ si, const int* __restrict__ ti,
    const float* __restrict__ user_emb, const float* __restrict__ item_s,
    const float* __restrict__ item_t,
    float* __restrict__ u_e, float* __restrict__ si_e, float* __restrict__ ti_e,
    // h_relu
    const float* __restrict__ his_s, const float* __restrict__ his_t,
    const float* __restrict__ dw1_s, const float* __restrict__ db1_s,
    const float* __restrict__ dw1_t, const float* __restrict__ db1_t,
    float* __restrict__ h_s, float* __restrict__ h_t)
{
    int bid = blockIdx.x, t = threadIdx.x;
    if (bid < PB_GATHER_) {
        int tid = bid * 256 + t;
        if (tid >= 3 * B_ * 8) return;
        int n = tid >> 3, c = tid & 7;
        int which = n >> 11, b = n & (B_ - 1);
        int row;
        const float4* base0;
        float* outp;
        if (which == 0)      { int id = si[b]; row = id;             base0 = (const float4*)item_s + (size_t)id * 8; outp = si_e; }
        else if (which == 1) { int id = u[b];  row = NS_ + id;       base0 = (const float4*)user_emb + (size_t)id * 8; outp = u_e; }
        else                 { int id = ti[b]; row = NS_ + NU_ + id; base0 = (const float4*)item_t + (size_t)id * 8; outp = ti_e; }
        float4 k0 = base0[c];
        float4 k1 = ((const float4*)E1)[(size_t)row * 8 + c];
        float4 k2 = ((const float4*)E2)[(size_t)row * 8 + c];
        float4 k3 = ((const float4*)E3c)[(size_t)slot3[row] * 8 + c];
        float4* orow = (float4*)(outp + (size_t)b * 128);
        orow[0 * 8 + c] = k0;
        orow[1 * 8 + c] = k1;
        orow[2 * 8 + c] = k2;
        orow[3 * 8 + c] = k3;
    } else {
        int b2 = bid - PB_GATHER_;
        int dom = b2 >> 9, sub = b2 & 511;
        const float* his = dom ? his_t : his_s;
        const float* w1  = dom ? dw1_t : dw1_s;
        const float* b1  = dom ? db1_t : db1_s;
        float* h         = dom ? h_t   : h_s;
        int b = sub * 4 + (t >> 6);
        int m = t & 63;
        float acc = b1[m];
        #pragma unroll
        for (int j = 0; j < 32; j++) acc += his[b * 32 + j] * w1[j * 64 + m];
        h[b * 64 + m] = fmaxf(acc, 0.f);
    }
}

// ===========================================================================
// Meta GEMM (bf16 MFMA): out[b,e] = sum_k q[b,k] * w2t[e,k],
// q[b, m*128+d] = h[b,m]*u_e[b,d] generated during LDS staging.
// Block: 64x128 tile, 4 waves 2x2. Split-K = 8 -> partials P, no atomics.
// ===========================================================================
__global__ __launch_bounds__(256) void meta_gemm(
    const float* __restrict__ h_s, const float* __restrict__ h_t,
    const float* __restrict__ ue,
    const unsigned short* __restrict__ w2t_s, const unsigned short* __restrict__ w2t_t,
    float* __restrict__ P)     // [2][8][B][128]
{
    __shared__ unsigned short As[64 * 72];
    __shared__ unsigned short Bs[128 * 72];

    int mt = blockIdx.x & 31, dom = blockIdx.x >> 5;
    int ks = blockIdx.y;
    const float* h = dom ? h_t : h_s;
    const unsigned short* w2t = dom ? w2t_t : w2t_s;

    int t = threadIdx.x;
    int ar = t >> 2, aseg = t & 3;
    int bn = t >> 1, bhalf = t & 1;
    int w = t >> 6, lane = t & 63;
    int quad = lane >> 4, l16 = lane & 15;
    int wm = (w & 1) * 32, wn = (w >> 1) * 64;

    f32x4 acc[8];
    #pragma unroll
    for (int i = 0; i < 8; i++) { acc[i][0]=0.f; acc[i][1]=0.f; acc[i][2]=0.f; acc[i][3]=0.f; }

    for (int ch = 0; ch < 16; ch++) {
        int kb = ks * 1024 + ch * 64;
        __syncthreads();
        {
            int gm = mt * 64 + ar;
            int m_idx = kb >> 7;
            int d0 = (kb & 127) + aseg * 16;
            float hv = h[gm * 64 + m_idx];
            const float4* up = (const float4*)(ue + (size_t)gm * 128 + d0);
            float4 x0 = up[0], x1 = up[1], x2 = up[2], x3 = up[3];
            uint4 A0, A1;
            A0.x = bfpack(hv*x0.x, hv*x0.y); A0.y = bfpack(hv*x0.z, hv*x0.w);
            A0.z = bfpack(hv*x1.x, hv*x1.y); A0.w = bfpack(hv*x1.z, hv*x1.w);
            A1.x = bfpack(hv*x2.x, hv*x2.y); A1.y = bfpack(hv*x2.z, hv*x2.w);
            A1.z = bfpack(hv*x3.x, hv*x3.y); A1.w = bfpack(hv*x3.z, hv*x3.w);
            uint4* sa = (uint4*)(As + ar * 72 + aseg * 16);
            sa[0] = A0; sa[1] = A1;
        }
        {
            const uint4* gb = (const uint4*)(w2t + (size_t)bn * GK_ + kb + bhalf * 32);
            uint4* sb = (uint4*)(Bs + bn * 72 + bhalf * 32);
            sb[0] = gb[0]; sb[1] = gb[1]; sb[2] = gb[2]; sb[3] = gb[3];
        }
        __syncthreads();
        #pragma unroll
        for (int kk = 0; kk < 2; kk++) {
            int ko = kk * 32 + quad * 8;
            bf16x8 a0 = *(const bf16x8*)(As + (wm + l16) * 72 + ko);
            bf16x8 a1 = *(const bf16x8*)(As + (wm + 16 + l16) * 72 + ko);
            #pragma unroll
            for (int nt = 0; nt < 4; nt++) {
                bf16x8 bfr = *(const bf16x8*)(Bs + (wn + nt * 16 + l16) * 72 + ko);
                acc[nt]     = __builtin_amdgcn_mfma_f32_16x16x32_bf16(a0, bfr, acc[nt],     0, 0, 0);
                acc[4 + nt] = __builtin_amdgcn_mfma_f32_16x16x32_bf16(a1, bfr, acc[4 + nt], 0, 0, 0);
            }
        }
    }
    float* op = P + ((size_t)dom * 8 + ks) * B_ * 128;
    #pragma unroll
    for (int ma = 0; ma < 2; ma++)
        #pragma unroll
        for (int nt = 0; nt < 4; nt++) {
            int row = mt * 64 + wm + ma * 16 + quad * 4;
            int col = wn + nt * 16 + l16;
            f32x4 v = acc[ma * 4 + nt];
            op[(size_t)(row + 0) * 128 + col] = v[0];
            op[(size_t)(row + 1) * 128 + col] = v[1];
            op[(size_t)(row + 2) * 128 + col] = v[2];
            op[(size_t)(row + 3) * 128 + col] = v[3];
        }
}

// ===========================================================================
// NCF heads, tiled: grid (B_/16, 2), 512 threads, 16 samples per block.
// Weights read once per 16 samples; 4-sample register blocking with float4
// LDS broadcast reads (4 independent FMA chains per thread).
// x = [ sum_ks P[dom][ks][b] + u_e@b2meta | pair_e ]
// ===========================================================================
__global__ __launch_bounds__(512) void ncf_kernel(
    const float* __restrict__ P, const float* __restrict__ u_e,
    const float* __restrict__ b2_s, const float* __restrict__ b2_t,
    const float* __restrict__ si_e, const float* __restrict__ ti_e,
    const float* __restrict__ w1_s, const float* __restrict__ b1_s,
    const float* __restrict__ w2_s, const float* __restrict__ bb2_s,
    const float* __restrict__ dw_s, const float* __restrict__ db_s,
    const float* __restrict__ w1_t, const float* __restrict__ b1_t,
    const float* __restrict__ w2_t, const float* __restrict__ bb2_t,
    const float* __restrict__ dw_t, const float* __restrict__ db_t,
    float* __restrict__ out)
{
    int tile = blockIdx.x, dom = blockIdx.y, t = threadIdx.x;
    int b0 = tile * NCF_TILE_;
    const float* Pd     = P + (size_t)dom * 8 * B_ * 128;
    const float* b2meta = dom ? b2_t : b2_s;
    const float* pair_e = dom ? ti_e : si_e;
    const float* w1 = dom ? w1_t : w1_s;
    const float* b1 = dom ? b1_t : b1_s;
    const float* w2 = dom ? w2_t : w2_s;
    const float* bb2 = dom ? bb2_t : bb2_s;
    const float* dw = dom ? dw_t : dw_s;
    const float* db = dom ? db_t : db_s;

    __shared__ float ues[NCF_TILE_ * 128];   // 8 KB
    __shared__ float xs[NCF_TILE_ * 256];    // 16 KB
    __shared__ float h1s[NCF_TILE_ * 128];   // 8 KB
    __shared__ float h2s[NCF_TILE_ * 64];    // 4 KB

    // stage u_e tile and pair_e (into x second half); 2048 floats each
    {
        float4 v = ((const float4*)(u_e + (size_t)b0 * 128))[t];
        ((float4*)ues)[t] = v;
        float4 pv = ((const float4*)(pair_e + (size_t)b0 * 128))[t];
        int s = t >> 5, c4 = t & 31;
        ((float4*)(xs + s * 256 + 128))[c4] = pv;
    }
    __syncthreads();

    int j = t & 127, g = t >> 7;          // 4 groups x 4 samples
    // ---- phase 1: x[:,0:128] = sum_ks P + ue @ b2meta ----
    {
        float acc[4];
        #pragma unroll
        for (int ss = 0; ss < 4; ss++) {
            int b = b0 + g * 4 + ss;
            float a = 0.f;
            #pragma unroll
            for (int ks = 0; ks < 8; ks++)
                a += Pd[(size_t)ks * B_ * 128 + (size_t)b * 128 + j];
            acc[ss] = a;
        }
        for (int dc = 0; dc < 32; dc++) {
            float wa = b2meta[(dc * 4 + 0) * 128 + j];
            float wb = b2meta[(dc * 4 + 1) * 128 + j];
            float wc = b2meta[(dc * 4 + 2) * 128 + j];
            float wd = b2meta[(dc * 4 + 3) * 128 + j];
            #pragma unroll
            for (int ss = 0; ss < 4; ss++) {
                float4 uv = ((const float4*)(ues + (g * 4 + ss) * 128))[dc];
                acc[ss] += uv.x * wa + uv.y * wb + uv.z * wc + uv.w * wd;
            }
        }
        #pragma unroll
        for (int ss = 0; ss < 4; ss++) xs[(g * 4 + ss) * 256 + j] = acc[ss];
    }
    __syncthreads();

    // ---- phase 2: h1 = relu(x @ w1 + b1) ----
    {
        float b1v = b1[j];
        float acc[4] = {b1v, b1v, b1v, b1v};
        for (int kc = 0; kc < 64; kc++) {
            float wa = w1[(kc * 4 + 0) * 128 + j];
            float wb = w1[(kc * 4 + 1) * 128 + j];
            float wc = w1[(kc * 4 + 2) * 128 + j];
            float wd = w1[(kc * 4 + 3) * 128 + j];
            #pragma unroll
            for (int ss = 0; ss < 4; ss++) {
                float4 xv = ((const float4*)(xs + (g * 4 + ss) * 256))[kc];
                acc[ss] += xv.x * wa + xv.y * wb + xv.z * wc + xv.w * wd;
            }
        }
        #pragma unroll
        for (int ss = 0; ss < 4; ss++)
            h1s[(g * 4 + ss) * 128 + j] = fmaxf(acc[ss], 0.f);
    }
    __syncthreads();

    // ---- phase 3: h2 = relu(h1 @ w2 + bb2) ----
    {
        int m = t & 63, g2 = t >> 6;      // 8 groups x 2 samples
        float bv = bb2[m];
        float acc[2] = {bv, bv};
        for (int kc = 0; kc < 32; kc++) {
            float wa = w2[(kc * 4 + 0) * 64 + m];
            float wb = w2[(kc * 4 + 1) * 64 + m];
            float wc = w2[(kc * 4 + 2) * 64 + m];
            float wd = w2[(kc * 4 + 3) * 64 + m];
            #pragma unroll
            for (int ss = 0; ss < 2; ss++) {
                float4 hv = ((const float4*)(h1s + (g2 * 2 + ss) * 128))[kc];
                acc[ss] += hv.x * wa + hv.y * wb + hv.z * wc + hv.w * wd;
            }
        }
        #pragma unroll
        for (int ss = 0; ss < 2; ss++)
            h2s[(g2 * 2 + ss) * 64 + m] = fmaxf(acc[ss], 0.f);
    }
    __syncthreads();

    // ---- phase 4: out = sigmoid(h2 @ dw + db) ----
    {
        int s = t >> 5, l = t & 31;
        float sum = h2s[s * 64 + l] * dw[l] + h2s[s * 64 + 32 + l] * dw[32 + l];
        #pragma unroll
        for (int off = 16; off > 0; off >>= 1) sum += __shfl_down(sum, off, 32);
        if (l == 0) {
            float z = sum + db[0];
            out[(size_t)dom * B_ + b0 + s] = 1.f / (1.f + expf(-z));
        }
    }
}

// ===========================================================================
extern "C" void kernel_launch(void* const* d_in, const int* in_sizes, int n_in,
                              void* d_out, int out_size, void* d_ws, size_t ws_size,
                              hipStream_t stream)
{
    const int*   u          = (const int*)  d_in[0];
    const int*   si         = (const int*)  d_in[1];
    const int*   ti         = (const int*)  d_in[2];
    const int*   src_seq    = (const int*)  d_in[3];
    const int*   tgt_seq    = (const int*)  d_in[4];
    const int*   adj_rows   = (const int*)  d_in[5];
    const int*   adj_cols   = (const int*)  d_in[6];
    const float* adj_vals   = (const float*)d_in[7];
    const float* user_emb   = (const float*)d_in[8];
    const float* item_s_emb = (const float*)d_in[9];
    const float* item_t_emb = (const float*)d_in[10];
    const float* attn_s_w1  = (const float*)d_in[11];
    const float* attn_s_b1  = (const float*)d_in[12];
    const float* attn_s_w2  = (const float*)d_in[13];
    const float* attn_t_w1  = (const float*)d_in[14];
    const float* attn_t_b1  = (const float*)d_in[15];
    const float* attn_t_w2  = (const float*)d_in[16];
    const float* dec_ss_w1  = (const float*)d_in[17];
    const float* dec_ss_b1  = (const float*)d_in[18];
    const float* dec_ss_w2  = (const float*)d_in[19];
    const float* dec_ss_b2  = (const float*)d_in[20];
    const float* dec_tt_w1  = (const float*)d_in[21];
    const float* dec_tt_b1  = (const float*)d_in[22];
    const float* dec_tt_w2  = (const float*)d_in[23];
    const float* dec_tt_b2  = (const float*)d_in[24];
    const float* mlp_s_w1   = (const float*)d_in[25];
    const float* mlp_s_b1   = (const float*)d_in[26];
    const float* mlp_s_w2   = (const float*)d_in[27];
    const float* mlp_s_b2   = (const float*)d_in[28];
    const float* dense_s_w  = (const float*)d_in[29];
    const float* dense_s_b  = (const float*)d_in[30];
    const float* mlp_t_w1   = (const float*)d_in[31];
    const float* mlp_t_b1   = (const float*)d_in[32];
    const float* mlp_t_w2   = (const float*)d_in[33];
    const float* mlp_t_b2   = (const float*)d_in[34];
    const float* dense_t_w  = (const float*)d_in[35];
    const float* dense_t_b  = (const float*)d_in[36];

    // workspace layout (all offsets 16B-aligned)
    char* p = (char*)d_ws;
    float* E1    = (float*)p;              p += (size_t)NN_ * 32 * 4;        // 51.2 MB
    float* E2    = (float*)p;              p += (size_t)NN_ * 32 * 4;        // 51.2 MB
    unsigned short* Ebf  = (unsigned short*)p; p += (size_t)NN_ * 32 * 2;    // 25.6 MB
    unsigned short* E1bf = (unsigned short*)p; p += (size_t)NN_ * 32 * 2;    // 25.6 MB
    int2*  partA = (int2*)p;               p += (size_t)NB_ * CAPA_ * 8;     // 10.5 MB
    int2*  partB = (int2*)p;               p += (size_t)NB_ * CAPB_ * 8;     // 4.2 MB
    int*   slot3 = (int*)p;                p += (size_t)400384 * 4;
    int*   marks = (int*)p;                                                  // mark1|mark2
    unsigned char* mark1 = (unsigned char*)p; p += 400384;
    unsigned char* mark2 = (unsigned char*)p; p += 400384;
    float* E3c   = (float*)p;              p += (size_t)3 * B_ * 32 * 4;     // 786 KB
    int*   bcurA = (int*)p;                p += NB_ * 4;
    int*   bcurB = (int*)p;                p += NB_ * 4;
    float* his_s = (float*)p;              p += (size_t)B_ * 32 * 4;
    float* his_t = (float*)p;              p += (size_t)B_ * 32 * 4;
    float* u_e   = (float*)p;              p += (size_t)B_ * 128 * 4;
    float* si_e  = (float*)p;              p += (size_t)B_ * 128 * 4;
    float* ti_e  = (float*)p;              p += (size_t)B_ * 128 * 4;
    float* h_s   = (float*)p;              p += (size_t)B_ * 64 * 4;
    float* h_t   = (float*)p;              p += (size_t)B_ * 64 * 4;
    float* P     = (float*)p;              p += (size_t)2 * 8 * B_ * 128 * 4;
    unsigned short* w2t_s = (unsigned short*)p; p += (size_t)128 * GK_ * 2;
    unsigned short* w2t_t = (unsigned short*)p; p += (size_t)128 * GK_ * 2;

    // 1. setup (fused): attn + w2 cvt + emb bf16 table + init (heavy blocks first)
    setup_kernel<<<SB_GRID_, 256, 0, stream>>>(item_s_emb, user_emb, item_t_emb,
                                               Ebf, slot3, marks, E3c, bcurA, bcurB,
                                               u, src_seq, tgt_seq,
                                               attn_s_w1, attn_s_b1, attn_s_w2,
                                               attn_t_w1, attn_t_b1, attn_t_w2,
                                               his_s, his_t,
                                               dec_ss_w2, dec_tt_w2, w2t_s, w2t_t);
    // 2. seeds
    mark_seeds<<<24, 256, 0, stream>>>(u, si, ti, slot3, mark1, mark2);
    // 3-4. demand marking (4 edges/thread)
    int m4Blocks = (NNZ_ / 4 + 255) / 256;
    mark_pass<<<m4Blocks, 256, 0, stream>>>(adj_rows, adj_cols, slot3, mark2, mark2, 1);
    mark_pass<<<m4Blocks, 256, 0, stream>>>(adj_rows, adj_cols, slot3, mark2, mark1, 0);
    // 5. one-pass bucket partition (245 blocks x 8192 edges)
    partition_edges<<<245, 512, 0, stream>>>(adj_rows, adj_cols, adj_vals,
                                             mark1, mark2, bcurA, bcurB, partA, partB);
    // 6-8. graph propagation (E1 fp32 gated to slot3 rows only)
    hop_csr<<<NB_, 512, 0, stream>>>(bcurA, partA, CAPA_, Ebf,  mark1, slot3, E1, E1bf);
    hop_csr<<<NB_, 512, 0, stream>>>(bcurB, partB, CAPB_, E1bf, mark2, nullptr, E2, nullptr);
    hop3_part<<<NB_, 256, 0, stream>>>(bcurB, partB, slot3, E2, E3c);
    // 9. prep: gather + h_relu
    prep_kernel<<<PB_TOT_, 256, 0, stream>>>(E1, E2, E3c, slot3, u, si, ti,
                                             user_emb, item_s_emb, item_t_emb,
                                             u_e, si_e, ti_e,
                                             his_s, his_t,
                                             dec_ss_w1, dec_ss_b1,
                                             dec_tt_w1, dec_tt_b1, h_s, h_t);
    // 10. meta MFMA GEMM (split-K partials, no atomics)
    meta_gemm<<<dim3(64, 8), 256, 0, stream>>>(h_s, h_t, u_e, w2t_s, w2t_t, P);
    // 11. NCF heads (both domains, 16-sample tiles)
    ncf_kernel<<<dim3(B_ / NCF_TILE_, 2), 512, 0, stream>>>(P, u_e, dec_ss_b2, dec_tt_b2,
                                                si_e, ti_e,
                                                mlp_s_w1, mlp_s_b1, mlp_s_w2, mlp_s_b2,
                                                dense_s_w, dense_s_b,
                                                mlp_t_w1, mlp_t_b1, mlp_t_w2, mlp_t_b2,
                                                dense_t_w, dense_t_b,
                                                (float*)d_out);
}

// Round 7
// 406.479 us; speedup vs baseline: 1.0176x; 1.0013x over previous
//
#include <hip/hip_runtime.h>
#include <hip/hip_bf16.h>

#define NU_ 200000
#define NS_ 100000
#define NT_ 100000
#define NN_ (NS_ + NU_ + NT_)   // 400000
#define D_ 32
#define DK_ 128
#define META_ 64
#define B_ 2048
#define L_ 50
#define NNZ_ 2000000
#define GK_ 8192                 // meta GEMM K = 64*128

#define RPB_ 391                 // rows per bucket
#define NB_ 1024                 // buckets (NB_*RPB_ = 400384 >= NN_)
#define STAGE_CAP_ 4096          // partition staging capacity (>10 sigma margin)
#define CAPA_ 1280               // partA per-bucket capacity (mean ~830, sd ~29)
#define CAPB_ 512                // partB per-bucket capacity (mean ~180, sd ~13)

// setup kernel block ranges: heavy attn first, then w2cvt, then streaming
#define SB_EMB_   6250           // NN_*4 / 256
#define IN4_SLOT3_ 100096        // 400384 ints / 4
#define IN4_MARKS_ 50048         // 800768 bytes / 16
#define IN4_E3C_   49152        // 196608 floats / 4
#define IN4_TOT_  (IN4_SLOT3_ + IN4_MARKS_ + IN4_E3C_)        // 199296
#define SB_INIT_  ((IN4_TOT_ + 2048 + 255) / 256)             // 787
#define SB_ATT0_  0
#define SB_W2C0_  1024
#define SB_EMB0_  2048
#define SB_INIT0_ (SB_EMB0_ + SB_EMB_)                        // 8298
#define SB_GRID_  (SB_INIT0_ + SB_INIT_)                      // 9085

// prep kernel block ranges
#define PB_GATHER_ 192
#define PB_TOT_    (PB_GATHER_ + 1024)

// ncf tiling
#define NCF_TILE_ 16

typedef __attribute__((ext_vector_type(8))) short bf16x8;
typedef __attribute__((ext_vector_type(4))) float f32x4;

// single-instruction RNE pack of two f32 -> packed bf16x2 (lo=a, hi=b)
__device__ inline unsigned bfpack(float a, float b) {
    unsigned r;
    asm("v_cvt_pk_bf16_f32 %0, %1, %2" : "=v"(r) : "v"(a), "v"(b));
    return r;
}
__device__ inline float bf2f(short s) {
    return __uint_as_float(((unsigned)(unsigned short)s) << 16);
}

// ===========================================================================
// Setup (fused): attn pooling | w2 cvt | emb bf16 table | workspace init.
// Attn matvec uses wave-UNIFORM weight operands (scalar s_load path) — no
// LDS for w1/b1/w2: kills 256 ds_read_b128/lane + 32-way staging conflicts.
// ===========================================================================
__global__ __launch_bounds__(256) void setup_kernel(
    const float* __restrict__ item_s, const float* __restrict__ user_e,
    const float* __restrict__ item_t, unsigned short* __restrict__ tab,
    int* __restrict__ slot3, int* __restrict__ marks /* mark1|mark2 contiguous */,
    float* __restrict__ E3c, int* __restrict__ bcurA, int* __restrict__ bcurB,
    // attn pooling
    const int* __restrict__ u,
    const int* __restrict__ seq_s, const int* __restrict__ seq_t,
    const float* __restrict__ aw1_s, const float* __restrict__ ab1_s,
    const float* __restrict__ aw2_s,
    const float* __restrict__ aw1_t, const float* __restrict__ ab1_t,
    const float* __restrict__ aw2_t,
    float* __restrict__ his_s, float* __restrict__ his_t,
    // w2 cvt
    const float* __restrict__ dw2_s, const float* __restrict__ dw2_t,
    unsigned short* __restrict__ o_s, unsigned short* __restrict__ o_t)
{
    __shared__ float att[4][64];
    __shared__ int   ids[4][52];

    int bid = blockIdx.x, t = threadIdx.x;
    if (bid < SB_W2C0_) {
        // ---- attention pooling: 4 samples per block (1 wave each), same dom ----
        int aid = bid;
        int dom = aid >> 9;
        const int* seq = dom ? seq_t : seq_s;
        const float* emb = dom ? item_t : item_s;
        const float* w1 = dom ? aw1_t : aw1_s;
        const float* b1 = dom ? ab1_t : ab1_s;
        const float* w2 = dom ? aw2_t : aw2_s;
        float* out = dom ? his_t : his_s;

        int w = t >> 6, l = t & 63;
        int b = (aid & 511) * 4 + w;
        int uid = u[b];
        int lq = (l < L_) ? l : (L_ - 1);
        int id = seq[uid * L_ + lq];
        const float4* ep = (const float4*)(emb + (size_t)id * 32);
        float e[32];
        #pragma unroll
        for (int q = 0; q < 8; q++) {
            float4 v = ep[q];
            e[4*q+0] = v.x; e[4*q+1] = v.y; e[4*q+2] = v.z; e[4*q+3] = v.w;
        }
        // h[i] accumulators in VGPRs; weights via wave-uniform scalar loads
        float h[32];
        #pragma unroll
        for (int i = 0; i < 32; i++) h[i] = b1[i];
        #pragma unroll
        for (int jj = 0; jj < 32; jj++) {
            float ej = e[jj];
            const float* wrow = w1 + jj * 32;
            #pragma unroll
            for (int i = 0; i < 32; i++) h[i] += ej * wrow[i];
        }
        float acc = 0.f;
        #pragma unroll
        for (int i = 0; i < 32; i++) acc += fmaxf(h[i], 0.f) * w2[i];

        float logit = (l < L_) ? (acc - (id == 0 ? 1e8f : 0.f)) : -1e30f;
        float m = logit;
        for (int off = 32; off > 0; off >>= 1) m = fmaxf(m, __shfl_down(m, off, 64));
        m = __shfl(m, 0, 64);
        float ex = (l < L_) ? expf(logit - m) : 0.f;
        float s = ex;
        for (int off = 32; off > 0; off >>= 1) s += __shfl_down(s, off, 64);
        s = __shfl(s, 0, 64);
        att[w][l] = ex / s;                 // wave-private LDS row: no barrier needed
        if (l < L_) ids[w][l] = id;
        // weighted re-gather of e (L3-resident), split across half-waves
        {
            int d = l & 31, half = l >> 5;
            int q0 = half * 25;
            float o = 0.f;
            #pragma unroll
            for (int q = 0; q < 25; q++) {
                int qq = q0 + q;
                o += att[w][qq] * emb[(size_t)ids[w][qq] * 32 + d];
            }
            o += __shfl_xor(o, 32, 64);
            if (l < 32) out[b * 32 + l] = o;
        }
    } else if (bid < SB_EMB0_) {
        // ---- w2 -> bf16 transposed cvt (inputs only) ----
        int b3 = bid - SB_W2C0_;
        int dom = b3 >> 9, sub = b3 & 511;
        const float* w2 = dom ? dw2_t : dw2_s;
        unsigned short* o = dom ? o_t : o_s;
        int tid = sub * 256 + t;
        int nn = tid & 127, k8 = tid >> 7;
        float v[8];
        #pragma unroll
        for (int i = 0; i < 8; i++) v[i] = w2[(size_t)(k8 * 8 + i) * 128 + nn];
        uint4 r;
        r.x = bfpack(v[0], v[1]); r.y = bfpack(v[2], v[3]);
        r.z = bfpack(v[4], v[5]); r.w = bfpack(v[6], v[7]);
        *(uint4*)(o + (size_t)nn * GK_ + k8 * 8) = r;
    } else if (bid < SB_INIT0_) {
        int tid = (bid - SB_EMB0_) * 256 + t;            // < NN_*4
        int row = tid >> 2, seg = tid & 3;
        const float* src;
        if (row < NS_)            src = item_s + (size_t)row * 32;
        else if (row < NS_ + NU_) src = user_e + (size_t)(row - NS_) * 32;
        else                      src = item_t + (size_t)(row - NS_ - NU_) * 32;
        const float4* sp = (const float4*)(src + seg * 8);
        float4 a = sp[0], b = sp[1];
        uint4 r;
        r.x = bfpack(a.x, a.y); r.y = bfpack(a.z, a.w);
        r.z = bfpack(b.x, b.y); r.w = bfpack(b.z, b.w);
        *(uint4*)(tab + (size_t)row * 32 + seg * 8) = r;
    } else {
        int idx = (bid - SB_INIT0_) * 256 + t;
        if (idx < IN4_SLOT3_) {
            ((int4*)slot3)[idx] = make_int4(-1, -1, -1, -1);
        } else if (idx < IN4_SLOT3_ + IN4_MARKS_) {
            ((int4*)marks)[idx - IN4_SLOT3_] = make_int4(0, 0, 0, 0);
        } else if (idx < IN4_TOT_) {
            ((int4*)E3c)[idx - IN4_SLOT3_ - IN4_MARKS_] = make_int4(0, 0, 0, 0);
        } else {
            int c = idx - IN4_TOT_;
            if (c < NB_)            bcurA[c] = c * CAPA_;
            else if (c < 2 * NB_)   bcurB[c - NB_] = (c - NB_) * CAPB_;
        }
    }
}

// ===========================================================================
// Demand marking. Seeds: rows needed in E3 (and gathered from E1/E2).
// ===========================================================================
__global__ __launch_bounds__(256) void mark_seeds(
    const int* __restrict__ u, const int* __restrict__ si, const int* __restrict__ ti,
    int* __restrict__ slot3, unsigned char* __restrict__ mark1,
    unsigned char* __restrict__ mark2)
{
    int n = blockIdx.x * 256 + threadIdx.x;
    if (n >= 3 * B_) return;
    int which = n >> 11, b = n & (B_ - 1);
    int row = (which == 0) ? si[b] : (which == 1) ? NS_ + u[b] : NS_ + NU_ + ti[b];
    slot3[row] = n;          // racy for dup rows: any winner is fine (shared slot)
    mark1[row] = 1;
    mark2[row] = 1;
}

// mark propagation one hop backward: 4 edges/thread via int4 loads.
__global__ __launch_bounds__(256) void mark_pass(
    const int* __restrict__ rows, const int* __restrict__ cols,
    const int* __restrict__ slot3, const unsigned char* __restrict__ msrc,
    unsigned char* __restrict__ mdst, int use_slot)
{
    int j4 = blockIdx.x * 256 + threadIdx.x;
    if (j4 >= NNZ_ / 4) return;
    int4 r = ((const int4*)rows)[j4];
    int4 c = ((const int4*)cols)[j4];
    if (use_slot) {
        if (slot3[r.x] >= 0) mdst[c.x] = 1;
        if (slot3[r.y] >= 0) mdst[c.y] = 1;
        if (slot3[r.z] >= 0) mdst[c.z] = 1;
        if (slot3[r.w] >= 0) mdst[c.w] = 1;
    } else {
        if (msrc[r.x]) mdst[c.x] = 1;
        if (msrc[r.y]) mdst[c.y] = 1;
        if (msrc[r.z]) mdst[c.z] = 1;
        if (msrc[r.w]) mdst[c.w] = 1;
    }
}

// ===========================================================================
// One-pass partition into strided per-bucket regions (no global histogram).
// 245 blocks x 8192 edges (16/thread): amortizes the fixed per-block
// 1024-bucket hist+scan cost (490-block variant regressed — round 5).
// Payload: meta = local_row<<19 | col ; val.
// ===========================================================================
__global__ __launch_bounds__(512) void partition_edges(
    const int* __restrict__ rows, const int* __restrict__ cols,
    const float* __restrict__ vals,
    const unsigned char* __restrict__ mark1, const unsigned char* __restrict__ mark2,
    int* __restrict__ bcurA, int* __restrict__ bcurB,
    int2* __restrict__ partA, int2* __restrict__ partB)
{
    __shared__ int hist[NB_], sstart[NB_], sbase[NB_], scur[NB_];
    __shared__ int2 stage[STAGE_CAP_];
    __shared__ unsigned short stageb[STAGE_CAP_];
    __shared__ int stotal;

    int t = threadIdx.x;
    for (int i = t; i < NB_; i += 512) hist[i] = 0;
    __syncthreads();

    int base = blockIdx.x * 8192;
    int mybkt[16]; int2 mye[16]; unsigned myB = 0;
    #pragma unroll
    for (int i = 0; i < 16; i++) {
        int j = base + i * 512 + t;
        mybkt[i] = -1;
        if (j < NNZ_) {
            int r = rows[j];
            if (mark1[r]) {               // mark2 subset of mark1
                int bb = r / RPB_;
                int lr = r - bb * RPB_;
                mye[i] = make_int2((lr << 19) | cols[j], __float_as_int(vals[j]));
                mybkt[i] = bb;
                if (mark2[r]) myB |= (1u << i);
                atomicAdd(&hist[bb], 1);
            }
        }
    }
    __syncthreads();
    // ---- phase A: block-local scan of hist, reserve global runs, stage ----
    for (int i = t; i < NB_; i += 512) sstart[i] = hist[i];
    __syncthreads();
    for (int off = 1; off < NB_; off <<= 1) {
        int x0 = (t >= off) ? sstart[t - off] : 0;
        int x1 = (t + 512 >= off) ? sstart[t + 512 - off] : 0;
        __syncthreads();
        sstart[t] += x0; sstart[t + 512] += x1;
        __syncthreads();
    }
    if (t == 0) stotal = sstart[NB_ - 1];
    __syncthreads();
    int tot = stotal;
    for (int i = t; i < NB_; i += 512) {
        int cnt = hist[i];
        sstart[i] -= cnt;                             // exclusive
        sbase[i] = cnt ? atomicAdd(&bcurA[i], cnt) : 0;
        scur[i] = 0;
    }
    __syncthreads();

    if (tot <= STAGE_CAP_) {
        #pragma unroll
        for (int i = 0; i < 16; i++) {
            int bb = mybkt[i];
            if (bb >= 0) {
                int p = atomicAdd(&scur[bb], 1);
                int s = sstart[bb] + p;
                stage[s] = mye[i];
                stageb[s] = (unsigned short)bb;
            }
        }
        __syncthreads();
        for (int i = t; i < tot; i += 512) {
            int bb = stageb[i];
            int pos = sbase[bb] + (i - sstart[bb]);
            if (pos < (bb + 1) * CAPA_) partA[pos] = stage[i];
        }
    } else {
        // overflow fallback (statistically unreachable): direct scatter
        #pragma unroll
        for (int i = 0; i < 16; i++) {
            int bb = mybkt[i];
            if (bb >= 0) {
                int p = atomicAdd(&scur[bb], 1);
                int pos = sbase[bb] + p;
                if (pos < (bb + 1) * CAPA_) partA[pos] = mye[i];
            }
        }
    }
    __syncthreads();
    // ---- phase B: aggregate counts, reserve, direct scatter ----
    for (int i = t; i < NB_; i += 512) hist[i] = 0;
    __syncthreads();
    #pragma unroll
    for (int i = 0; i < 16; i++)
        if (myB & (1u << i)) atomicAdd(&hist[mybkt[i]], 1);
    __syncthreads();
    for (int i = t; i < NB_; i += 512) {
        sbase[i] = hist[i] ? atomicAdd(&bcurB[i], hist[i]) : 0;
        scur[i] = 0;
    }
    __syncthreads();
    #pragma unroll
    for (int i = 0; i < 16; i++) {
        if (myB & (1u << i)) {
            int bb = mybkt[i];
            int p = atomicAdd(&scur[bb], 1);
            int pos = sbase[bb] + p;
            if (pos < (bb + 1) * CAPB_) partB[pos] = mye[i];
        }
    }
}

// ===========================================================================
// Bucket SpMV hop, NO fp atomics: edges register-staged (single global read),
// within-bucket counting sort by row (LDS histogram + scan + scatter), then
// per-row REGISTER accumulation.
// fgate (optional): write fp32 output only for rows with fgate[row]>=0.
// ===========================================================================
__global__ __launch_bounds__(512) void hop_csr(
    const int* __restrict__ bcur, const int2* __restrict__ part, int cap,
    const unsigned short* __restrict__ tab,
    const unsigned char* __restrict__ markw,
    const int* __restrict__ fgate,
    float* __restrict__ yf, unsigned short* __restrict__ ybf)
{
    __shared__ int2 sorted[CAPA_];        // 10.2 KB
    __shared__ int cnt[RPB_];             // counts -> cursors
    __shared__ int scanb[512];            // inclusive scan of counts

    int t = threadIdx.x;
    int bkt = blockIdx.x;
    int e0 = bkt * cap;
    int n = bcur[bkt] - e0;
    if (n > cap) n = cap;

    // register-stage up to 3 edges/thread (covers CAPA_=1280 and CAPB_=512)
    int2 mye[3]; int myl[3];
    #pragma unroll
    for (int i = 0; i < 3; i++) {
        int j = i * 512 + t;
        myl[i] = -1;
        if (j < n) {
            mye[i] = part[e0 + j];
            myl[i] = (mye[i].x >> 19) & 0x3FF;
        }
    }
    for (int i = t; i < RPB_; i += 512) cnt[i] = 0;
    __syncthreads();
    #pragma unroll
    for (int i = 0; i < 3; i++)
        if (myl[i] >= 0) atomicAdd(&cnt[myl[i]], 1);
    __syncthreads();
    scanb[t] = (t < RPB_) ? cnt[t] : 0;
    __syncthreads();
    for (int off = 1; off < 512; off <<= 1) {
        int x = (t >= off) ? scanb[t - off] : 0;
        __syncthreads();
        scanb[t] += x;
        __syncthreads();
    }
    if (t < RPB_) cnt[t] = scanb[t] - cnt[t];
    __syncthreads();
    #pragma unroll
    for (int i = 0; i < 3; i++)
        if (myl[i] >= 0) {
            int p2 = atomicAdd(&cnt[myl[i]], 1);
            sorted[p2] = mye[i];
        }
    __syncthreads();
    int chunk = t & 3;
    int row0 = bkt * RPB_;
    for (int r = t >> 2; r < RPB_; r += 128) {
        int grow = row0 + r;
        if (grow >= NN_ || !markw[grow]) continue;
        int eb = (r == 0) ? 0 : scanb[r - 1];
        int ee = scanb[r];
        float racc[8] = {0.f, 0.f, 0.f, 0.f, 0.f, 0.f, 0.f, 0.f};
        for (int e = eb; e < ee; e++) {
            int2 ed = sorted[e];
            int col = ed.x & 0x7FFFF;
            float vv = __int_as_float(ed.y);
            bf16x8 x = *(const bf16x8*)(tab + (size_t)col * 32 + chunk * 8);
            #pragma unroll
            for (int k = 0; k < 8; k++) racc[k] += vv * bf2f(x[k]);
        }
        float4 o0 = {racc[0], racc[1], racc[2], racc[3]};
        float4 o1 = {racc[4], racc[5], racc[6], racc[7]};
        if (!fgate || fgate[grow] >= 0) {
            float4* yp = (float4*)(yf + (size_t)grow * 32 + chunk * 8);
            yp[0] = o0; yp[1] = o1;
        }
        if (ybf) {
            uint4 pk;
            pk.x = bfpack(o0.x, o0.y); pk.y = bfpack(o0.z, o0.w);
            pk.z = bfpack(o1.x, o1.y); pk.w = bfpack(o1.z, o1.w);
            *(uint4*)(ybf + (size_t)grow * 32 + chunk * 8) = pk;
        }
    }
}

// ===========================================================================
// Hop 3 over compact partB: global atomics into E3c (fp32 E2 source).
// ===========================================================================
__global__ __launch_bounds__(256) void hop3_part(
    const int* __restrict__ bcurB, const int2* __restrict__ partB,
    const int* __restrict__ slot3,
    const float* __restrict__ E2, float* __restrict__ E3c)
{
    int t = threadIdx.x;
    int bkt = blockIdx.x;
    int e0 = bkt * CAPB_;
    int e1 = bcurB[bkt];
    int emax = e0 + CAPB_;
    if (e1 > emax) e1 = emax;
    int c = t & 7;
    for (int i = e0 + (t >> 3); i < e1; i += 32) {
        int2 e = partB[i];
        int lr = (e.x >> 19) & 0x3FF;
        int s = slot3[bkt * RPB_ + lr];
        if (s < 0) continue;
        int col = e.x & 0x7FFFF;
        float v = __int_as_float(e.y);
        float4 xv = ((const float4*)E2)[(size_t)col * 8 + c];
        float* p = E3c + (size_t)s * 32 + c * 4;
        unsafeAtomicAdd(p + 0, v * xv.x);
        unsafeAtomicAdd(p + 1, v * xv.y);
        unsafeAtomicAdd(p + 2, v * xv.z);
        unsafeAtomicAdd(p + 3, v * xv.w);
    }
}

// ===========================================================================
// Prep (fused): [0,192) gather_simple | [192,1216) h_relu
// ===========================================================================
__global__ __launch_bounds__(256) void prep_kernel(
    // gather
    const float* __restrict__ E1, const float* __restrict__ E2,
    const float* __restrict__ E3c, const int* __restrict__ slot3,
    const int* __restrict__ u, const int* __restrict__ si, const int* __restrict__ ti,
    const float* __restrict__ user_emb, const float* __restrict__ item_s,
    const float* __restrict__ item_t,
    float* __restrict__ u_e, float* __restrict__ si_e, float* __restrict__ ti_e,
    // h_relu
    const float* __restrict__ his_s, const float* __restrict__ his_t,
    const float* __restrict__ dw1_s, const float* __restrict__ db1_s,
    const float* __restrict__ dw1_t, const float* __restrict__ db1_t,
    float* __restrict__ h_s, float* __restrict__ h_t)
{
    int bid = blockIdx.x, t = threadIdx.x;
    if (bid < PB_GATHER_) {
        int tid = bid * 256 + t;
        if (tid >= 3 * B_ * 8) return;
        int n = tid >> 3, c = tid & 7;
        int which = n >> 11, b = n & (B_ - 1);
        int row;
        const float4* base0;
        float* outp;
        if (which == 0)      { int id = si[b]; row = id;             base0 = (const float4*)item_s + (size_t)id * 8; outp = si_e; }
        else if (which == 1) { int id = u[b];  row = NS_ + id;       base0 = (const float4*)user_emb + (size_t)id * 8; outp = u_e; }
        else                 { int id = ti[b]; row = NS_ + NU_ + id; base0 = (const float4*)item_t + (size_t)id * 8; outp = ti_e; }
        float4 k0 = base0[c];
        float4 k1 = ((const float4*)E1)[(size_t)row * 8 + c];
        float4 k2 = ((const float4*)E2)[(size_t)row * 8 + c];
        float4 k3 = ((const float4*)E3c)[(size_t)slot3[row] * 8 + c];
        float4* orow = (float4*)(outp + (size_t)b * 128);
        orow[0 * 8 + c] = k0;
        orow[1 * 8 + c] = k1;
        orow[2 * 8 + c] = k2;
        orow[3 * 8 + c] = k3;
    } else {
        int b2 = bid - PB_GATHER_;
        int dom = b2 >> 9, sub = b2 & 511;
        const float* his = dom ? his_t : his_s;
        const float* w1  = dom ? dw1_t : dw1_s;
        const float* b1  = dom ? db1_t : db1_s;
        float* h         = dom ? h_t   : h_s;
        int b = sub * 4 + (t >> 6);
        int m = t & 63;
        float acc = b1[m];
        #pragma unroll
        for (int j = 0; j < 32; j++) acc += his[b * 32 + j] * w1[j * 64 + m];
        h[b * 64 + m] = fmaxf(acc, 0.f);
    }
}

// ===========================================================================
// Meta GEMM (bf16 MFMA): out[b,e] = sum_k q[b,k] * w2t[e,k],
// q[b, m*128+d] = h[b,m]*u_e[b,d] generated during LDS staging.
// Block: 64x128 tile, 4 waves 2x2. Split-K = 8 -> partials P, no atomics.
// ===========================================================================
__global__ __launch_bounds__(256) void meta_gemm(
    const float* __restrict__ h_s, const float* __restrict__ h_t,
    const float* __restrict__ ue,
    const unsigned short* __restrict__ w2t_s, const unsigned short* __restrict__ w2t_t,
    float* __restrict__ P)     // [2][8][B][128]
{
    __shared__ unsigned short As[64 * 72];
    __shared__ unsigned short Bs[128 * 72];

    int mt = blockIdx.x & 31, dom = blockIdx.x >> 5;
    int ks = blockIdx.y;
    const float* h = dom ? h_t : h_s;
    const unsigned short* w2t = dom ? w2t_t : w2t_s;

    int t = threadIdx.x;
    int ar = t >> 2, aseg = t & 3;
    int bn = t >> 1, bhalf = t & 1;
    int w = t >> 6, lane = t & 63;
    int quad = lane >> 4, l16 = lane & 15;
    int wm = (w & 1) * 32, wn = (w >> 1) * 64;

    f32x4 acc[8];
    #pragma unroll
    for (int i = 0; i < 8; i++) { acc[i][0]=0.f; acc[i][1]=0.f; acc[i][2]=0.f; acc[i][3]=0.f; }

    for (int ch = 0; ch < 16; ch++) {
        int kb = ks * 1024 + ch * 64;
        __syncthreads();
        {
            int gm = mt * 64 + ar;
            int m_idx = kb >> 7;
            int d0 = (kb & 127) + aseg * 16;
            float hv = h[gm * 64 + m_idx];
            const float4* up = (const float4*)(ue + (size_t)gm * 128 + d0);
            float4 x0 = up[0], x1 = up[1], x2 = up[2], x3 = up[3];
            uint4 A0, A1;
            A0.x = bfpack(hv*x0.x, hv*x0.y); A0.y = bfpack(hv*x0.z, hv*x0.w);
            A0.z = bfpack(hv*x1.x, hv*x1.y); A0.w = bfpack(hv*x1.z, hv*x1.w);
            A1.x = bfpack(hv*x2.x, hv*x2.y); A1.y = bfpack(hv*x2.z, hv*x2.w);
            A1.z = bfpack(hv*x3.x, hv*x3.y); A1.w = bfpack(hv*x3.z, hv*x3.w);
            uint4* sa = (uint4*)(As + ar * 72 + aseg * 16);
            sa[0] = A0; sa[1] = A1;
        }
        {
            const uint4* gb = (const uint4*)(w2t + (size_t)bn * GK_ + kb + bhalf * 32);
            uint4* sb = (uint4*)(Bs + bn * 72 + bhalf * 32);
            sb[0] = gb[0]; sb[1] = gb[1]; sb[2] = gb[2]; sb[3] = gb[3];
        }
        __syncthreads();
        #pragma unroll
        for (int kk = 0; kk < 2; kk++) {
            int ko = kk * 32 + quad * 8;
            bf16x8 a0 = *(const bf16x8*)(As + (wm + l16) * 72 + ko);
            bf16x8 a1 = *(const bf16x8*)(As + (wm + 16 + l16) * 72 + ko);
            #pragma unroll
            for (int nt = 0; nt < 4; nt++) {
                bf16x8 bfr = *(const bf16x8*)(Bs + (wn + nt * 16 + l16) * 72 + ko);
                acc[nt]     = __builtin_amdgcn_mfma_f32_16x16x32_bf16(a0, bfr, acc[nt],     0, 0, 0);
                acc[4 + nt] = __builtin_amdgcn_mfma_f32_16x16x32_bf16(a1, bfr, acc[4 + nt], 0, 0, 0);
            }
        }
    }
    float* op = P + ((size_t)dom * 8 + ks) * B_ * 128;
    #pragma unroll
    for (int ma = 0; ma < 2; ma++)
        #pragma unroll
        for (int nt = 0; nt < 4; nt++) {
            int row = mt * 64 + wm + ma * 16 + quad * 4;
            int col = wn + nt * 16 + l16;
            f32x4 v = acc[ma * 4 + nt];
            op[(size_t)(row + 0) * 128 + col] = v[0];
            op[(size_t)(row + 1) * 128 + col] = v[1];
            op[(size_t)(row + 2) * 128 + col] = v[2];
            op[(size_t)(row + 3) * 128 + col] = v[3];
        }
}

// ===========================================================================
// NCF heads, tiled: grid (B_/16, 2), 512 threads, 16 samples per block.
// Weights read once per 16 samples; 4-sample register blocking with float4
// LDS broadcast reads (4 independent FMA chains per thread).
// x = [ sum_ks P[dom][ks][b] + u_e@b2meta | pair_e ]
// ===========================================================================
__global__ __launch_bounds__(512) void ncf_kernel(
    const float* __restrict__ P, const float* __restrict__ u_e,
    const float* __restrict__ b2_s, const float* __restrict__ b2_t,
    const float* __restrict__ si_e, const float* __restrict__ ti_e,
    const float* __restrict__ w1_s, const float* __restrict__ b1_s,
    const float* __restrict__ w2_s, const float* __restrict__ bb2_s,
    const float* __restrict__ dw_s, const float* __restrict__ db_s,
    const float* __restrict__ w1_t, const float* __restrict__ b1_t,
    const float* __restrict__ w2_t, const float* __restrict__ bb2_t,
    const float* __restrict__ dw_t, const float* __restrict__ db_t,
    float* __restrict__ out)
{
    int tile = blockIdx.x, dom = blockIdx.y, t = threadIdx.x;
    int b0 = tile * NCF_TILE_;
    const float* Pd     = P + (size_t)dom * 8 * B_ * 128;
    const float* b2meta = dom ? b2_t : b2_s;
    const float* pair_e = dom ? ti_e : si_e;
    const float* w1 = dom ? w1_t : w1_s;
    const float* b1 = dom ? b1_t : b1_s;
    const float* w2 = dom ? w2_t : w2_s;
    const float* bb2 = dom ? bb2_t : bb2_s;
    const float* dw = dom ? dw_t : dw_s;
    const float* db = dom ? db_t : db_s;

    __shared__ float ues[NCF_TILE_ * 128];   // 8 KB
    __shared__ float xs[NCF_TILE_ * 256];    // 16 KB
    __shared__ float h1s[NCF_TILE_ * 128];   // 8 KB
    __shared__ float h2s[NCF_TILE_ * 64];    // 4 KB

    // stage u_e tile and pair_e (into x second half); 2048 floats each
    {
        float4 v = ((const float4*)(u_e + (size_t)b0 * 128))[t];
        ((float4*)ues)[t] = v;
        float4 pv = ((const float4*)(pair_e + (size_t)b0 * 128))[t];
        int s = t >> 5, c4 = t & 31;
        ((float4*)(xs + s * 256 + 128))[c4] = pv;
    }
    __syncthreads();

    int j = t & 127, g = t >> 7;          // 4 groups x 4 samples
    // ---- phase 1: x[:,0:128] = sum_ks P + ue @ b2meta ----
    {
        float acc[4];
        #pragma unroll
        for (int ss = 0; ss < 4; ss++) {
            int b = b0 + g * 4 + ss;
            float a = 0.f;
            #pragma unroll
            for (int ks = 0; ks < 8; ks++)
                a += Pd[(size_t)ks * B_ * 128 + (size_t)b * 128 + j];
            acc[ss] = a;
        }
        for (int dc = 0; dc < 32; dc++) {
            float wa = b2meta[(dc * 4 + 0) * 128 + j];
            float wb = b2meta[(dc * 4 + 1) * 128 + j];
            float wc = b2meta[(dc * 4 + 2) * 128 + j];
            float wd = b2meta[(dc * 4 + 3) * 128 + j];
            #pragma unroll
            for (int ss = 0; ss < 4; ss++) {
                float4 uv = ((const float4*)(ues + (g * 4 + ss) * 128))[dc];
                acc[ss] += uv.x * wa + uv.y * wb + uv.z * wc + uv.w * wd;
            }
        }
        #pragma unroll
        for (int ss = 0; ss < 4; ss++) xs[(g * 4 + ss) * 256 + j] = acc[ss];
    }
    __syncthreads();

    // ---- phase 2: h1 = relu(x @ w1 + b1) ----
    {
        float b1v = b1[j];
        float acc[4] = {b1v, b1v, b1v, b1v};
        for (int kc = 0; kc < 64; kc++) {
            float wa = w1[(kc * 4 + 0) * 128 + j];
            float wb = w1[(kc * 4 + 1) * 128 + j];
            float wc = w1[(kc * 4 + 2) * 128 + j];
            float wd = w1[(kc * 4 + 3) * 128 + j];
            #pragma unroll
            for (int ss = 0; ss < 4; ss++) {
                float4 xv = ((const float4*)(xs + (g * 4 + ss) * 256))[kc];
                acc[ss] += xv.x * wa + xv.y * wb + xv.z * wc + xv.w * wd;
            }
        }
        #pragma unroll
        for (int ss = 0; ss < 4; ss++)
            h1s[(g * 4 + ss) * 128 + j] = fmaxf(acc[ss], 0.f);
    }
    __syncthreads();

    // ---- phase 3: h2 = relu(h1 @ w2 + bb2) ----
    {
        int m = t & 63, g2 = t >> 6;      // 8 groups x 2 samples
        float bv = bb2[m];
        float acc[2] = {bv, bv};
        for (int kc = 0; kc < 32; kc++) {
            float wa = w2[(kc * 4 + 0) * 64 + m];
            float wb = w2[(kc * 4 + 1) * 64 + m];
            float wc = w2[(kc * 4 + 2) * 64 + m];
            float wd = w2[(kc * 4 + 3) * 64 + m];
            #pragma unroll
            for (int ss = 0; ss < 2; ss++) {
                float4 hv = ((const float4*)(h1s + (g2 * 2 + ss) * 128))[kc];
                acc[ss] += hv.x * wa + hv.y * wb + hv.z * wc + hv.w * wd;
            }
        }
        #pragma unroll
        for (int ss = 0; ss < 2; ss++)
            h2s[(g2 * 2 + ss) * 64 + m] = fmaxf(acc[ss], 0.f);
    }
    __syncthreads();

    // ---- phase 4: out = sigmoid(h2 @ dw + db) ----
    {
        int s = t >> 5, l = t & 31;
        float sum = h2s[s * 64 + l] * dw[l] + h2s[s * 64 + 32 + l] * dw[32 + l];
        #pragma unroll
        for (int off = 16; off > 0; off >>= 1) sum += __shfl_down(sum, off, 32);
        if (l == 0) {
            float z = sum + db[0];
            out[(size_t)dom * B_ + b0 + s] = 1.f / (1.f + expf(-z));
        }
    }
}

// ===========================================================================
extern "C" void kernel_launch(void* const* d_in, const int* in_sizes, int n_in,
                              void* d_out, int out_size, void* d_ws, size_t ws_size,
                              hipStream_t stream)
{
    const int*   u          = (const int*)  d_in[0];
    const int*   si         = (const int*)  d_in[1];
    const int*   ti         = (const int*)  d_in[2];
    const int*   src_seq    = (const int*)  d_in[3];
    const int*   tgt_seq    = (const int*)  d_in[4];
    const int*   adj_rows   = (const int*)  d_in[5];
    const int*   adj_cols   = (const int*)  d_in[6];
    const float* adj_vals   = (const float*)d_in[7];
    const float* user_emb   = (const float*)d_in[8];
    const float* item_s_emb = (const float*)d_in[9];
    const float* item_t_emb = (const float*)d_in[10];
    const float* attn_s_w1  = (const float*)d_in[11];
    const float* attn_s_b1  = (const float*)d_in[12];
    const float* attn_s_w2  = (const float*)d_in[13];
    const float* attn_t_w1  = (const float*)d_in[14];
    const float* attn_t_b1  = (const float*)d_in[15];
    const float* attn_t_w2  = (const float*)d_in[16];
    const float* dec_ss_w1  = (const float*)d_in[17];
    const float* dec_ss_b1  = (const float*)d_in[18];
    const float* dec_ss_w2  = (const float*)d_in[19];
    const float* dec_ss_b2  = (const float*)d_in[20];
    const float* dec_tt_w1  = (const float*)d_in[21];
    const float* dec_tt_b1  = (const float*)d_in[22];
    const float* dec_tt_w2  = (const float*)d_in[23];
    const float* dec_tt_b2  = (const float*)d_in[24];
    const float* mlp_s_w1   = (const float*)d_in[25];
    const float* mlp_s_b1   = (const float*)d_in[26];
    const float* mlp_s_w2   = (const float*)d_in[27];
    const float* mlp_s_b2   = (const float*)d_in[28];
    const float* dense_s_w  = (const float*)d_in[29];
    const float* dense_s_b  = (const float*)d_in[30];
    const float* mlp_t_w1   = (const float*)d_in[31];
    const float* mlp_t_b1   = (const float*)d_in[32];
    const float* mlp_t_w2   = (const float*)d_in[33];
    const float* mlp_t_b2   = (const float*)d_in[34];
    const float* dense_t_w  = (const float*)d_in[35];
    const float* dense_t_b  = (const float*)d_in[36];

    // workspace layout (all offsets 16B-aligned)
    char* p = (char*)d_ws;
    float* E1    = (float*)p;              p += (size_t)NN_ * 32 * 4;        // 51.2 MB
    float* E2    = (float*)p;              p += (size_t)NN_ * 32 * 4;        // 51.2 MB
    unsigned short* Ebf  = (unsigned short*)p; p += (size_t)NN_ * 32 * 2;    // 25.6 MB
    unsigned short* E1bf = (unsigned short*)p; p += (size_t)NN_ * 32 * 2;    // 25.6 MB
    int2*  partA = (int2*)p;               p += (size_t)NB_ * CAPA_ * 8;     // 10.5 MB
    int2*  partB = (int2*)p;               p += (size_t)NB_ * CAPB_ * 8;     // 4.2 MB
    int*   slot3 = (int*)p;                p += (size_t)400384 * 4;
    int*   marks = (int*)p;                                                  // mark1|mark2
    unsigned char* mark1 = (unsigned char*)p; p += 400384;
    unsigned char* mark2 = (unsigned char*)p; p += 400384;
    float* E3c   = (float*)p;              p += (size_t)3 * B_ * 32 * 4;     // 786 KB
    int*   bcurA = (int*)p;                p += NB_ * 4;
    int*   bcurB = (int*)p;                p += NB_ * 4;
    float* his_s = (float*)p;              p += (size_t)B_ * 32 * 4;
    float* his_t = (float*)p;              p += (size_t)B_ * 32 * 4;
    float* u_e   = (float*)p;              p += (size_t)B_ * 128 * 4;
    float* si_e  = (float*)p;              p += (size_t)B_ * 128 * 4;
    float* ti_e  = (float*)p;              p += (size_t)B_ * 128 * 4;
    float* h_s   = (float*)p;              p += (size_t)B_ * 64 * 4;
    float* h_t   = (float*)p;              p += (size_t)B_ * 64 * 4;
    float* P     = (float*)p;              p += (size_t)2 * 8 * B_ * 128 * 4;
    unsigned short* w2t_s = (unsigned short*)p; p += (size_t)128 * GK_ * 2;
    unsigned short* w2t_t = (unsigned short*)p; p += (size_t)128 * GK_ * 2;

    // 1. setup (fused): attn + w2 cvt + emb bf16 table + init (heavy blocks first)
    setup_kernel<<<SB_GRID_, 256, 0, stream>>>(item_s_emb, user_emb, item_t_emb,
                                               Ebf, slot3, marks, E3c, bcurA, bcurB,
                                               u, src_seq, tgt_seq,
                                               attn_s_w1, attn_s_b1, attn_s_w2,
                                               attn_t_w1, attn_t_b1, attn_t_w2,
                                               his_s, his_t,
                                               dec_ss_w2, dec_tt_w2, w2t_s, w2t_t);
    // 2. seeds
    mark_seeds<<<24, 256, 0, stream>>>(u, si, ti, slot3, mark1, mark2);
    // 3-4. demand marking (4 edges/thread)
    int m4Blocks = (NNZ_ / 4 + 255) / 256;
    mark_pass<<<m4Blocks, 256, 0, stream>>>(adj_rows, adj_cols, slot3, mark2, mark2, 1);
    mark_pass<<<m4Blocks, 256, 0, stream>>>(adj_rows, adj_cols, slot3, mark2, mark1, 0);
    // 5. one-pass bucket partition (245 blocks x 8192 edges)
    partition_edges<<<245, 512, 0, stream>>>(adj_rows, adj_cols, adj_vals,
                                             mark1, mark2, bcurA, bcurB, partA, partB);
    // 6-8. graph propagation (E1 fp32 gated to slot3 rows only)
    hop_csr<<<NB_, 512, 0, stream>>>(bcurA, partA, CAPA_, Ebf,  mark1, slot3, E1, E1bf);
    hop_csr<<<NB_, 512, 0, stream>>>(bcurB, partB, CAPB_, E1bf, mark2, nullptr, E2, nullptr);
    hop3_part<<<NB_, 256, 0, stream>>>(bcurB, partB, slot3, E2, E3c);
    // 9. prep: gather + h_relu
    prep_kernel<<<PB_TOT_, 256, 0, stream>>>(E1, E2, E3c, slot3, u, si, ti,
                                             user_emb, item_s_emb, item_t_emb,
                                             u_e, si_e, ti_e,
                                             his_s, his_t,
                                             dec_ss_w1, dec_ss_b1,
                                             dec_tt_w1, dec_tt_b1, h_s, h_t);
    // 10. meta MFMA GEMM (split-K partials, no atomics)
    meta_gemm<<<dim3(64, 8), 256, 0, stream>>>(h_s, h_t, u_e, w2t_s, w2t_t, P);
    // 11. NCF heads (both domains, 16-sample tiles)
    ncf_kernel<<<dim3(B_ / NCF_TILE_, 2), 512, 0, stream>>>(P, u_e, dec_ss_b2, dec_tt_b2,
                                                si_e, ti_e,
                                                mlp_s_w1, mlp_s_b1, mlp_s_w2, mlp_s_b2,
                                                dense_s_w, dense_s_b,
                                                mlp_t_w1, mlp_t_b1, mlp_t_w2, mlp_t_b2,
                                                dense_t_w, dense_t_b,
                                                (float*)d_out);
}